// Round 12
// baseline (180.563 us; speedup 1.0000x reference)
//
#include <hip/hip_runtime.h>
#include <cstdint>
#include <cstddef>

typedef __attribute__((ext_vector_type(8))) short bf16x8;
typedef __attribute__((ext_vector_type(4))) float f32x4;

#define S_    2048
#define D_    1024
#define F_    2048
#define O_    1024
#define E_    8
#define KCAP  256
#define ROWS  512           // 2 batches * KCAP per expert
#define NTOK  4096          // B*S

#define BM 64
#define BN 64
#define BK 64
#define TILE_ELEMS (BM * BK)

// ---------- bf16 helpers ----------
__device__ __forceinline__ unsigned short f2bf(float f) {
  unsigned int u = __float_as_uint(f);
  u = (u + 0x7fffu + ((u >> 16) & 1u)) >> 16;   // RNE
  return (unsigned short)u;
}
__device__ __forceinline__ float bf2f(unsigned short h) {
  return __uint_as_float(((unsigned int)h) << 16);
}

// ---------- async global->LDS, 16B per lane, wave-uniform LDS base ----------
__device__ __forceinline__ void gload16(void* lds, const void* g) {
  auto gp = (__attribute__((address_space(1))) unsigned int*)(uintptr_t)g;
  auto lp = (__attribute__((address_space(3))) unsigned int*)(unsigned int)(uintptr_t)lds;
  __builtin_amdgcn_global_load_lds(gp, lp, 16, 0, 0);
}

// ---------- gating: logits (fp64 accum) + softmax probs + x->bf16 ----------
__global__ void gating_kernel(const float* __restrict__ x, const float* __restrict__ wg,
                              float* __restrict__ logits, float* __restrict__ probs,
                              unsigned short* __restrict__ xb) {
  const int wave = threadIdx.x >> 6, lane = threadIdx.x & 63;
  const int t = blockIdx.x * 4 + wave;
  const float* xr = x + (size_t)t * D_;
  double acc[8] = {0, 0, 0, 0, 0, 0, 0, 0};
  const int d0 = lane * 16;
#pragma unroll
  for (int i = 0; i < 4; i++) {
    float4 xv = *(const float4*)&xr[d0 + i * 4];
    union { ushort4 u4; unsigned short u[4]; } cv;
    cv.u[0] = f2bf(xv.x); cv.u[1] = f2bf(xv.y); cv.u[2] = f2bf(xv.z); cv.u[3] = f2bf(xv.w);
    *(ushort4*)&xb[(size_t)t * D_ + d0 + i * 4] = cv.u4;
    float xs[4] = {xv.x, xv.y, xv.z, xv.w};
#pragma unroll
    for (int j = 0; j < 4; j++) {
      const float4* wr = (const float4*)&wg[(size_t)(d0 + i * 4 + j) * 8];
      float4 w0 = wr[0], w1v = wr[1];
      double xd = (double)xs[j];
      acc[0] += xd * (double)w0.x;  acc[1] += xd * (double)w0.y;
      acc[2] += xd * (double)w0.z;  acc[3] += xd * (double)w0.w;
      acc[4] += xd * (double)w1v.x; acc[5] += xd * (double)w1v.y;
      acc[6] += xd * (double)w1v.z; acc[7] += xd * (double)w1v.w;
    }
  }
#pragma unroll
  for (int off = 32; off; off >>= 1) {
#pragma unroll
    for (int e = 0; e < 8; e++) acc[e] += __shfl_down(acc[e], off);
  }
  if (lane == 0) {
    double m = acc[0];
    for (int e = 1; e < 8; e++) m = acc[e] > m ? acc[e] : m;
    double p[8]; double s = 0;
    for (int e = 0; e < 8; e++) { p[e] = exp(acc[e] - m); s += p[e]; }
    const double inv = 1.0 / s;
    for (int e = 0; e < 8; e++) {
      logits[(size_t)t * 8 + e] = (float)acc[e];
      probs [(size_t)t * 8 + e] = (float)(p[e] * inv);
    }
  }
}

// ---------- per-expert transpose + fp32->bf16, 16B coalesced stores ----------
__global__ void transpose_cvt_kernel(const float* __restrict__ in, unsigned short* __restrict__ out,
                                     const int R, const int C) {
  __shared__ float t[64][65];
  const int e = blockIdx.z;
  const float* inp = in + (size_t)e * R * C;
  unsigned short* outp = out + (size_t)e * R * C;
  const int r0 = blockIdx.y * 64, c0 = blockIdx.x * 64;
  const int tid = threadIdx.x;
  const int lr = tid >> 4;          // 0..15
  const int lc = (tid & 15) * 4;    // 0..60
#pragma unroll
  for (int i = 0; i < 4; i++) {
    const int r = lr + i * 16;
    const float4 v = *(const float4*)&inp[(size_t)(r0 + r) * C + c0 + lc];
    t[r][lc] = v.x; t[r][lc + 1] = v.y; t[r][lc + 2] = v.z; t[r][lc + 3] = v.w;
  }
  __syncthreads();
  // store: each thread emits ushort8 (16B) of 8 consecutive R at fixed C
  const int r8 = (tid & 7) * 8;
#pragma unroll
  for (int it = 0; it < 2; it++) {
    const int c = (tid >> 3) + it * 32;
    union { bf16x8 v; unsigned short u[8]; } o;
#pragma unroll
    for (int j = 0; j < 8; j++) o.u[j] = f2bf(t[r8 + j][c]);
    *(bf16x8*)&outp[(size_t)(c0 + c) * R + r0 + r8] = o.v;
  }
}

// ---------- expert-choice top-k + deterministic per-token inverse index ----------
__global__ void topk_kernel(const float* __restrict__ logits, const float* __restrict__ probs,
                            int* __restrict__ sel, float* __restrict__ gate,
                            int* __restrict__ entry) {    // entry[tok][e] = row+1 (0 = absent)
  __shared__ unsigned int keys[S_];
  const int idx = blockIdx.x;       // 0..127 : (b,e) x 8 segments
  const int seg = idx & 7;
  const int be = idx >> 3;          // 0..15
  const int b = be >> 3;            // 0..1
  const int e = be & 7;
  const int tid = threadIdx.x;
  for (int i = tid; i < S_; i += 256) {
    unsigned int u = __float_as_uint(logits[((size_t)(b * S_ + i)) * E_ + e]);
    keys[i] = u ^ ((u & 0x80000000u) ? 0xFFFFFFFFu : 0x80000000u);
  }
  __syncthreads();
  const int s = seg * 256 + tid;
  const unsigned int vk = keys[s];
  const int wave = tid >> 6;
  const int W0 = seg * 256 + wave * 64;
  int rank = 0;
#pragma unroll 4
  for (int i = 0; i < W0; i += 4) {
    const uint4 kv = *(const uint4*)&keys[i];
    rank += (kv.x >= vk) + (kv.y >= vk) + (kv.z >= vk) + (kv.w >= vk);
  }
#pragma unroll
  for (int j = 0; j < 64; j++) {
    const int i = W0 + j;
    const unsigned int kv = keys[i];
    rank += (kv > vk) || (kv == vk && i < s);
  }
#pragma unroll 4
  for (int i = W0 + 64; i < S_; i += 4) {
    const uint4 kv = *(const uint4*)&keys[i];
    rank += (kv.x > vk) + (kv.y > vk) + (kv.z > vk) + (kv.w > vk);
  }
  const int tok = b * S_ + s;
  if (rank < KCAP) {
    const int row = b * KCAP + rank;
    sel  [e * ROWS + row] = tok;
    gate [e * ROWS + row] = probs[(size_t)tok * E_ + e];
    entry[tok * E_ + e]   = row + 1;
  } else {
    entry[tok * E_ + e]   = 0;
  }
}

// ====================== DARK: gemm1 BK=128, single-buffer 32KB, 5 blocks/CU ======================
// Tests whether halving the barrier-round count (8 vs 16) beats the TLP drop (20 vs 32 waves).
#define BK2 128
__global__ __launch_bounds__(256, 5) void gemm1_bk128_kernel(
    const unsigned short* __restrict__ xb, const unsigned short* __restrict__ w1t,
    const float* __restrict__ b1, const int* __restrict__ sel,
    unsigned short* __restrict__ hbuf) {
  __shared__ unsigned short As[64 * BK2];   // 16 KB
  __shared__ unsigned short Bs[64 * BK2];   // 16 KB
  const int bid = blockIdx.x;
  const int lid = (bid & 7) * 256 + (bid >> 3);
  const int e   = lid >> 8;
  const int rem = lid & 255;
  const int n0  = (rem >> 3) * BN;
  const int m0  = (rem & 7) * BM;
  const int tid = threadIdx.x;
  const int wave = tid >> 6, lane = tid & 63;
  const int wr = wave >> 1, wc = wave & 1;

  // staging: each gload16 covers 4 rows x 16 chunks of 16B (row = lane>>4, chunk = lane&15)
  const int srow4 = lane >> 4;              // 0..3
  const int sc = lane & 15;                 // chunk 0..15
  const unsigned short* asrc[4];
  const unsigned short* bsrc[4];
#pragma unroll
  for (int i = 0; i < 4; i++) {
    const int r = wave * 16 + i * 4 + srow4;
    const int tok = sel[e * ROWS + m0 + r];
    const int ch = sc ^ (r & 7);            // pre-swizzled source chunk
    asrc[i] = xb + (size_t)tok * D_ + ch * 8;
    bsrc[i] = w1t + ((size_t)e * F_ + n0 + r) * D_ + ch * 8;
  }

  f32x4 acc[2][2];
#pragma unroll
  for (int mi = 0; mi < 2; mi++)
#pragma unroll
    for (int nj = 0; nj < 2; nj++) acc[mi][nj] = (f32x4){0.f, 0.f, 0.f, 0.f};

  const int fr = lane & 15;

  for (int t = 0; t < D_ / BK2; t++) {      // 8 steps
    const int k0 = t * BK2;
#pragma unroll
    for (int i = 0; i < 4; i++) {
      gload16(&As[(wave * 16 + i * 4) * BK2], asrc[i] + k0);
      gload16(&Bs[(wave * 16 + i * 4) * BK2], bsrc[i] + k0);
    }
    __syncthreads();
#pragma unroll
    for (int kk = 0; kk < 4; kk++) {
      const int q = kk * 4 + (lane >> 4);   // chunk 0..15
      bf16x8 a[2], b[2];
#pragma unroll
      for (int mi = 0; mi < 2; mi++) {
        const int r = wr * 32 + mi * 16 + fr;
        a[mi] = *(const bf16x8*)&As[r * BK2 + ((q ^ (r & 7)) * 8)];
      }
#pragma unroll
      for (int nj = 0; nj < 2; nj++) {
        const int r = wc * 32 + nj * 16 + fr;
        b[nj] = *(const bf16x8*)&Bs[r * BK2 + ((q ^ (r & 7)) * 8)];
      }
#pragma unroll
      for (int mi = 0; mi < 2; mi++)
#pragma unroll
        for (int nj = 0; nj < 2; nj++)
          acc[mi][nj] = __builtin_amdgcn_mfma_f32_16x16x32_bf16(a[mi], b[nj], acc[mi][nj], 0, 0, 0);
    }
    __syncthreads();
  }

  const int lr = (lane >> 4) * 4;
#pragma unroll
  for (int mi = 0; mi < 2; mi++)
#pragma unroll
    for (int nj = 0; nj < 2; nj++)
#pragma unroll
      for (int rg = 0; rg < 4; rg++) {
        const int row = m0 + wr * 32 + mi * 16 + lr + rg;
        const int col = n0 + wc * 32 + nj * 16 + fr;
        float v = acc[mi][nj][rg] + b1[e * F_ + col];
        v = 0.5f * v * (1.0f + erff(v * 0.70710678118654752f));
        hbuf[((size_t)e * ROWS + row) * F_ + col] = f2bf(v);
      }
}

// ====================== GEMM1 (D1): single-buffer, 8 blocks/CU ======================
__global__ __launch_bounds__(256, 8) void gemm1_kernel(
    const unsigned short* __restrict__ xb, const unsigned short* __restrict__ w1t,
    const float* __restrict__ b1, const int* __restrict__ sel,
    unsigned short* __restrict__ hbuf) {
  __shared__ unsigned short As[TILE_ELEMS];   // 8 KB
  __shared__ unsigned short Bs[TILE_ELEMS];   // 8 KB
  const int bid = blockIdx.x;
  const int lid = (bid & 7) * 256 + (bid >> 3);
  const int e   = lid >> 8;
  const int rem = lid & 255;
  const int n0  = (rem >> 3) * BN;
  const int m0  = (rem & 7) * BM;
  const int tid = threadIdx.x;
  const int wave = tid >> 6, lane = tid & 63;
  const int wr = wave >> 1, wc = wave & 1;

  const int srow = lane >> 3;
  const int schunk = (lane & 7) ^ srow;
  const unsigned short* asrc[2];
  const unsigned short* bsrc[2];
#pragma unroll
  for (int j = 0; j < 2; j++) {
    const int r = wave * 16 + j * 8 + srow;
    const int tok = sel[e * ROWS + m0 + r];
    asrc[j] = xb + (size_t)tok * D_ + schunk * 8;
    bsrc[j] = w1t + ((size_t)e * F_ + n0 + r) * D_ + schunk * 8;
  }

  f32x4 acc[2][2];
#pragma unroll
  for (int mi = 0; mi < 2; mi++)
#pragma unroll
    for (int nj = 0; nj < 2; nj++) acc[mi][nj] = (f32x4){0.f, 0.f, 0.f, 0.f};

  const int fr = lane & 15;

  for (int t = 0; t < D_ / BK; t++) {
    const int k0 = t * BK;
#pragma unroll
    for (int j = 0; j < 2; j++) {
      gload16(&As[(wave * 16 + j * 8) * BK], asrc[j] + k0);
      gload16(&Bs[(wave * 16 + j * 8) * BK], bsrc[j] + k0);
    }
    __syncthreads();                 // staging complete (implicit vmcnt(0))
    bf16x8 a[2][2], b[2][2];
#pragma unroll
    for (int kk = 0; kk < 2; kk++) {
      const int xch = ((kk * 4 + (lane >> 4)) ^ (lane & 7)) * 8;
#pragma unroll
      for (int mi = 0; mi < 2; mi++)
        a[kk][mi] = *(const bf16x8*)&As[(wr * 32 + mi * 16 + fr) * BK + xch];
#pragma unroll
      for (int nj = 0; nj < 2; nj++)
        b[kk][nj] = *(const bf16x8*)&Bs[(wc * 32 + nj * 16 + fr) * BK + xch];
    }
#pragma unroll
    for (int kk = 0; kk < 2; kk++)
#pragma unroll
      for (int mi = 0; mi < 2; mi++)
#pragma unroll
        for (int nj = 0; nj < 2; nj++)
          acc[mi][nj] = __builtin_amdgcn_mfma_f32_16x16x32_bf16(a[kk][mi], b[kk][nj], acc[mi][nj], 0, 0, 0);
    __syncthreads();                 // all waves done reading before next overwrite
  }

  const int lr = (lane >> 4) * 4;
#pragma unroll
  for (int mi = 0; mi < 2; mi++)
#pragma unroll
    for (int nj = 0; nj < 2; nj++)
#pragma unroll
      for (int rg = 0; rg < 4; rg++) {
        const int row = m0 + wr * 32 + mi * 16 + lr + rg;
        const int col = n0 + wc * 32 + nj * 16 + fr;
        float v = acc[mi][nj][rg] + b1[e * F_ + col];
        v = 0.5f * v * (1.0f + erff(v * 0.70710678118654752f));   // exact GELU
        hbuf[((size_t)e * ROWS + row) * F_ + col] = f2bf(v);
      }
}

// ---------- row LayerNorm over F_, in place on bf16 h ----------
__global__ void ln_kernel(unsigned short* __restrict__ hbuf,
                          const float* __restrict__ g_ln, const float* __restrict__ b_ln) {
  const int row = blockIdx.x;          // 0..E_*ROWS-1
  const int e = row >> 9;
  unsigned short* hr = hbuf + (size_t)row * F_;
  const int tid = threadIdx.x;
  union { bf16x8 v; unsigned short u[8]; } u;
  u.v = *(const bf16x8*)&hr[tid * 8];
  float vals[8]; float s1 = 0.f, s2 = 0.f;
#pragma unroll
  for (int j = 0; j < 8; j++) { float f = bf2f(u.u[j]); vals[j] = f; s1 += f; s2 += f * f; }
#pragma unroll
  for (int off = 32; off; off >>= 1) { s1 += __shfl_down(s1, off); s2 += __shfl_down(s2, off); }
  __shared__ float rs[8];
  const int wave = tid >> 6, lane = tid & 63;
  if (lane == 0) { rs[wave] = s1; rs[wave + 4] = s2; }
  __syncthreads();
  const float t1 = rs[0] + rs[1] + rs[2] + rs[3];
  const float t2 = rs[4] + rs[5] + rs[6] + rs[7];
  const float mu = t1 * (1.f / F_);
  const float var = t2 * (1.f / F_) - mu * mu;   // biased var (jnp.var)
  const float rstd = rsqrtf(var + 1e-5f);
  const float4* gl4 = (const float4*)(g_ln + (size_t)e * F_ + tid * 8);
  const float4* bl4 = (const float4*)(b_ln + (size_t)e * F_ + tid * 8);
  float4 g0 = gl4[0], g1 = gl4[1], bb0 = bl4[0], bb1 = bl4[1];
  float gs[8] = {g0.x, g0.y, g0.z, g0.w, g1.x, g1.y, g1.z, g1.w};
  float bs[8] = {bb0.x, bb0.y, bb0.z, bb0.w, bb1.x, bb1.y, bb1.z, bb1.w};
  union { bf16x8 v; unsigned short u[8]; } o;
#pragma unroll
  for (int j = 0; j < 8; j++)
    o.u[j] = f2bf((vals[j] - mu) * rstd * gs[j] + bs[j]);
  *(bf16x8*)&hr[tid * 8] = o.v;
}

// ====================== GEMM2 partial: split-K x2, D1 structure, plain stores ======================
__global__ __launch_bounds__(256, 8) void gemm2_partial_kernel(
    const unsigned short* __restrict__ hbuf, // [E][ROWS][F_]
    const unsigned short* __restrict__ w2t,  // [E][O_][F_]
    float* __restrict__ part) {              // [2][E_*ROWS][O_]
  __shared__ unsigned short As[TILE_ELEMS];
  __shared__ unsigned short Bs[TILE_ELEMS];
  const int bid = blockIdx.x;
  const int lid = (bid & 7) * 256 + (bid >> 3);   // 8 XCDs x 256; expert-per-XCD
  const int e     = lid >> 8;
  const int rem   = lid & 255;
  const int khalf = rem & 1;
  const int m0    = ((rem >> 1) & 7) * BM;
  const int n0    = (rem >> 4) * BN;              // 16 O panels
  const int koff  = khalf * (F_ / 2);
  const int tid = threadIdx.x;
  const int wave = tid >> 6, lane = tid & 63;
  const int wr = wave >> 1, wc = wave & 1;

  const int srow = lane >> 3;
  const int schunk = (lane & 7) ^ srow;
  const unsigned short* asrc[2];
  const unsigned short* bsrc[2];
#pragma unroll
  for (int j = 0; j < 2; j++) {
    const int r = wave * 16 + j * 8 + srow;
    asrc[j] = hbuf + ((size_t)e * ROWS + m0 + r) * F_ + koff + schunk * 8;
    bsrc[j] = w2t + ((size_t)e * O_ + n0 + r) * F_ + koff + schunk * 8;
  }

  f32x4 acc[2][2];
#pragma unroll
  for (int mi = 0; mi < 2; mi++)
#pragma unroll
    for (int nj = 0; nj < 2; nj++) acc[mi][nj] = (f32x4){0.f, 0.f, 0.f, 0.f};

  const int fr = lane & 15;

  for (int t = 0; t < (F_ / 2) / BK; t++) {   // 16 steps
    const int k0 = t * BK;
#pragma unroll
    for (int j = 0; j < 2; j++) {
      gload16(&As[(wave * 16 + j * 8) * BK], asrc[j] + k0);
      gload16(&Bs[(wave * 16 + j * 8) * BK], bsrc[j] + k0);
    }
    __syncthreads();
    bf16x8 a[2][2], b[2][2];
#pragma unroll
    for (int kk = 0; kk < 2; kk++) {
      const int xch = ((kk * 4 + (lane >> 4)) ^ (lane & 7)) * 8;
#pragma unroll
      for (int mi = 0; mi < 2; mi++)
        a[kk][mi] = *(const bf16x8*)&As[(wr * 32 + mi * 16 + fr) * BK + xch];
#pragma unroll
      for (int nj = 0; nj < 2; nj++)
        b[kk][nj] = *(const bf16x8*)&Bs[(wc * 32 + nj * 16 + fr) * BK + xch];
    }
#pragma unroll
    for (int kk = 0; kk < 2; kk++)
#pragma unroll
      for (int mi = 0; mi < 2; mi++)
#pragma unroll
        for (int nj = 0; nj < 2; nj++)
          acc[mi][nj] = __builtin_amdgcn_mfma_f32_16x16x32_bf16(a[kk][mi], b[kk][nj], acc[mi][nj], 0, 0, 0);
    __syncthreads();
  }

  float* pbase = part + (size_t)khalf * (E_ * ROWS) * O_;
  const int lr = (lane >> 4) * 4;
#pragma unroll
  for (int mi = 0; mi < 2; mi++)
#pragma unroll
    for (int rg = 0; rg < 4; rg++) {
      const int row = m0 + wr * 32 + mi * 16 + lr + rg;
#pragma unroll
      for (int nj = 0; nj < 2; nj++) {
        const int col = n0 + wc * 32 + nj * 16 + fr;
        pbase[((size_t)(e * ROWS) + row) * O_ + col] = acc[mi][nj][rg];
      }
    }
}

// ---------- combine: out[tok] = sum_e gate * (p0 + p1 + b2[e]) ; atomic-free ----------
__global__ void combine_kernel(const float* __restrict__ part, const int* __restrict__ entry,
                               const float* __restrict__ gate, const float* __restrict__ b2,
                               float* __restrict__ out) {
  const int tok = blockIdx.x;
  const int c = threadIdx.x * 4;
  float4 acc = {0.f, 0.f, 0.f, 0.f};
#pragma unroll
  for (int e = 0; e < E_; e++) {
    const int r1 = entry[tok * E_ + e];
    if (r1) {
      const int idx = e * ROWS + (r1 - 1);
      const float g = gate[idx];
      const float4 p0 = *(const float4*)&part[(size_t)idx * O_ + c];
      const float4 p1 = *(const float4*)&part[(size_t)(E_ * ROWS + idx) * O_ + c];
      const float4 bb = *(const float4*)&b2[e * O_ + c];
      acc.x += g * (p0.x + p1.x + bb.x);
      acc.y += g * (p0.y + p1.y + bb.y);
      acc.z += g * (p0.z + p1.z + bb.z);
      acc.w += g * (p0.w + p1.w + bb.w);
    }
  }
  *(float4*)&out[(size_t)tok * O_ + c] = acc;
}

// ---------- launch ----------
extern "C" void kernel_launch(void* const* d_in, const int* in_sizes, int n_in,
                              void* d_out, int out_size, void* d_ws, size_t ws_size,
                              hipStream_t stream) {
  const float* x     = (const float*)d_in[0];
  const float* wg    = (const float*)d_in[1];
  const float* w1    = (const float*)d_in[2];
  const float* b1    = (const float*)d_in[3];
  const float* g_ln  = (const float*)d_in[4];
  const float* b_ln  = (const float*)d_in[5];
  const float* w2    = (const float*)d_in[6];
  const float* b2    = (const float*)d_in[7];
  float* out = (float*)d_out;
  float* out_logits = out + (size_t)NTOK * O_;

  char* wsb = (char*)d_ws;
  unsigned short* xb   = (unsigned short*)(wsb + 0);          // 8,388,608 B
  unsigned short* w1t  = (unsigned short*)(wsb + 8388608);    // 33,554,432 B (reused as part)
  unsigned short* w2t  = (unsigned short*)(wsb + 41943040);   // 33,554,432 B
  unsigned short* hbuf = (unsigned short*)(wsb + 75497472);   // 16,777,216 B
  float* probs = (float*)(wsb + 92274688);                    // 131,072 B
  int*   sel   = (int*)  (wsb + 92405760);                    // 16,384 B
  float* gate  = (float*)(wsb + 92422144);                    // 16,384 B
  int*   entry = (int*)  (wsb + 92438528);                    // 131,072 B
  float* part  = (float*)(wsb + 8388608);                     // aliases w1t (dead after gemm1)

  gating_kernel<<<NTOK / 4, 256, 0, stream>>>(x, wg, out_logits, probs, xb);
  transpose_cvt_kernel<<<dim3(F_ / 64, D_ / 64, E_), 256, 0, stream>>>(w1, w1t, D_, F_); // -> [F][D]
  transpose_cvt_kernel<<<dim3(O_ / 64, F_ / 64, E_), 256, 0, stream>>>(w2, w2t, F_, O_); // -> [O][F]
  topk_kernel<<<2 * E_ * 8, 256, 0, stream>>>(out_logits, probs, sel, gate, entry);

  // dark A/B probe: BK=128 gemm1 (output overwritten by canonical)
  gemm1_bk128_kernel<<<(F_ / BN) * (ROWS / BM) * E_, 256, 0, stream>>>(xb, w1t, b1, sel, hbuf);

  gemm1_kernel<<<(F_ / BN) * (ROWS / BM) * E_, 256, 0, stream>>>(xb, w1t, b1, sel, hbuf);
  ln_kernel<<<E_ * ROWS, 256, 0, stream>>>(hbuf, g_ln, b_ln);
  gemm2_partial_kernel<<<2048, 256, 0, stream>>>(hbuf, w2t, part);
  combine_kernel<<<NTOK, 256, 0, stream>>>(part, entry, gate, b2, out);
}

// Round 13
// 149.956 us; speedup vs baseline: 1.2041x; 1.2041x over previous
//
#include <hip/hip_runtime.h>
#include <cstdint>
#include <cstddef>

typedef __attribute__((ext_vector_type(8))) short bf16x8;
typedef __attribute__((ext_vector_type(4))) float f32x4;

#define S_    2048
#define D_    1024
#define F_    2048
#define O_    1024
#define E_    8
#define KCAP  256
#define ROWS  512           // 2 batches * KCAP per expert
#define NTOK  4096          // B*S

#define BM 64
#define BN 64
#define BK 64
#define TILE_ELEMS (BM * BK)

// ---------- bf16 helpers ----------
__device__ __forceinline__ unsigned short f2bf(float f) {
  unsigned int u = __float_as_uint(f);
  u = (u + 0x7fffu + ((u >> 16) & 1u)) >> 16;   // RNE
  return (unsigned short)u;
}
__device__ __forceinline__ float bf2f(unsigned short h) {
  return __uint_as_float(((unsigned int)h) << 16);
}

// ---------- async global->LDS, 16B per lane, wave-uniform LDS base ----------
__device__ __forceinline__ void gload16(void* lds, const void* g) {
  auto gp = (__attribute__((address_space(1))) unsigned int*)(uintptr_t)g;
  auto lp = (__attribute__((address_space(3))) unsigned int*)(unsigned int)(uintptr_t)lds;
  __builtin_amdgcn_global_load_lds(gp, lp, 16, 0, 0);
}

// ---------- gating: logits (fp64 accum) + softmax probs + x->bf16 ----------
__global__ void gating_kernel(const float* __restrict__ x, const float* __restrict__ wg,
                              float* __restrict__ logits, float* __restrict__ probs,
                              unsigned short* __restrict__ xb) {
  const int wave = threadIdx.x >> 6, lane = threadIdx.x & 63;
  const int t = blockIdx.x * 4 + wave;
  const float* xr = x + (size_t)t * D_;
  double acc[8] = {0, 0, 0, 0, 0, 0, 0, 0};
  const int d0 = lane * 16;
#pragma unroll
  for (int i = 0; i < 4; i++) {
    float4 xv = *(const float4*)&xr[d0 + i * 4];
    union { ushort4 u4; unsigned short u[4]; } cv;
    cv.u[0] = f2bf(xv.x); cv.u[1] = f2bf(xv.y); cv.u[2] = f2bf(xv.z); cv.u[3] = f2bf(xv.w);
    *(ushort4*)&xb[(size_t)t * D_ + d0 + i * 4] = cv.u4;
    float xs[4] = {xv.x, xv.y, xv.z, xv.w};
#pragma unroll
    for (int j = 0; j < 4; j++) {
      const float4* wr = (const float4*)&wg[(size_t)(d0 + i * 4 + j) * 8];
      float4 w0 = wr[0], w1v = wr[1];
      double xd = (double)xs[j];
      acc[0] += xd * (double)w0.x;  acc[1] += xd * (double)w0.y;
      acc[2] += xd * (double)w0.z;  acc[3] += xd * (double)w0.w;
      acc[4] += xd * (double)w1v.x; acc[5] += xd * (double)w1v.y;
      acc[6] += xd * (double)w1v.z; acc[7] += xd * (double)w1v.w;
    }
  }
#pragma unroll
  for (int off = 32; off; off >>= 1) {
#pragma unroll
    for (int e = 0; e < 8; e++) acc[e] += __shfl_down(acc[e], off);
  }
  if (lane == 0) {
    double m = acc[0];
    for (int e = 1; e < 8; e++) m = acc[e] > m ? acc[e] : m;
    double p[8]; double s = 0;
    for (int e = 0; e < 8; e++) { p[e] = exp(acc[e] - m); s += p[e]; }
    const double inv = 1.0 / s;
    for (int e = 0; e < 8; e++) {
      logits[(size_t)t * 8 + e] = (float)acc[e];
      probs [(size_t)t * 8 + e] = (float)(p[e] * inv);
    }
  }
}

// ---------- per-expert transpose + fp32->bf16, 16B coalesced stores ----------
__global__ void transpose_cvt_kernel(const float* __restrict__ in, unsigned short* __restrict__ out,
                                     const int R, const int C) {
  __shared__ float t[64][65];
  const int e = blockIdx.z;
  const float* inp = in + (size_t)e * R * C;
  unsigned short* outp = out + (size_t)e * R * C;
  const int r0 = blockIdx.y * 64, c0 = blockIdx.x * 64;
  const int tid = threadIdx.x;
  const int lr = tid >> 4;          // 0..15
  const int lc = (tid & 15) * 4;    // 0..60
#pragma unroll
  for (int i = 0; i < 4; i++) {
    const int r = lr + i * 16;
    const float4 v = *(const float4*)&inp[(size_t)(r0 + r) * C + c0 + lc];
    t[r][lc] = v.x; t[r][lc + 1] = v.y; t[r][lc + 2] = v.z; t[r][lc + 3] = v.w;
  }
  __syncthreads();
  // store: each thread emits ushort8 (16B) of 8 consecutive R at fixed C
  const int r8 = (tid & 7) * 8;
#pragma unroll
  for (int it = 0; it < 2; it++) {
    const int c = (tid >> 3) + it * 32;
    union { bf16x8 v; unsigned short u[8]; } o;
#pragma unroll
    for (int j = 0; j < 8; j++) o.u[j] = f2bf(t[r8 + j][c]);
    *(bf16x8*)&outp[(size_t)(c0 + c) * R + r0 + r8] = o.v;
  }
}

// ---------- expert-choice top-k + deterministic per-token inverse index ----------
__global__ void topk_kernel(const float* __restrict__ logits, const float* __restrict__ probs,
                            int* __restrict__ sel, float* __restrict__ gate,
                            int* __restrict__ entry) {    // entry[tok][e] = row+1 (0 = absent)
  __shared__ unsigned int keys[S_];
  const int idx = blockIdx.x;       // 0..127 : (b,e) x 8 segments
  const int seg = idx & 7;
  const int be = idx >> 3;          // 0..15
  const int b = be >> 3;            // 0..1
  const int e = be & 7;
  const int tid = threadIdx.x;
  for (int i = tid; i < S_; i += 256) {
    unsigned int u = __float_as_uint(logits[((size_t)(b * S_ + i)) * E_ + e]);
    keys[i] = u ^ ((u & 0x80000000u) ? 0xFFFFFFFFu : 0x80000000u);
  }
  __syncthreads();
  const int s = seg * 256 + tid;
  const unsigned int vk = keys[s];
  const int wave = tid >> 6;
  const int W0 = seg * 256 + wave * 64;
  int rank = 0;
#pragma unroll 4
  for (int i = 0; i < W0; i += 4) {
    const uint4 kv = *(const uint4*)&keys[i];
    rank += (kv.x >= vk) + (kv.y >= vk) + (kv.z >= vk) + (kv.w >= vk);
  }
#pragma unroll
  for (int j = 0; j < 64; j++) {
    const int i = W0 + j;
    const unsigned int kv = keys[i];
    rank += (kv > vk) || (kv == vk && i < s);
  }
#pragma unroll 4
  for (int i = W0 + 64; i < S_; i += 4) {
    const uint4 kv = *(const uint4*)&keys[i];
    rank += (kv.x > vk) + (kv.y > vk) + (kv.z > vk) + (kv.w > vk);
  }
  const int tok = b * S_ + s;
  if (rank < KCAP) {
    const int row = b * KCAP + rank;
    sel  [e * ROWS + row] = tok;
    gate [e * ROWS + row] = probs[(size_t)tok * E_ + e];
    entry[tok * E_ + e]   = row + 1;
  } else {
    entry[tok * E_ + e]   = 0;
  }
}

// ====================== GEMM1 (D1): single-buffer, 8 blocks/CU ======================
// 64x64x64, 4 waves, 16KB LDS single-buffer, gload16 + XOR swizzle, expert-per-XCD.
// Inter-block TLP (32 waves/CU) covers the per-step vmcnt(0) drain.
__global__ __launch_bounds__(256, 8) void gemm1_kernel(
    const unsigned short* __restrict__ xb, const unsigned short* __restrict__ w1t,
    const float* __restrict__ b1, const int* __restrict__ sel,
    unsigned short* __restrict__ hbuf) {
  __shared__ unsigned short As[TILE_ELEMS];   // 8 KB
  __shared__ unsigned short Bs[TILE_ELEMS];   // 8 KB
  const int bid = blockIdx.x;
  const int lid = (bid & 7) * 256 + (bid >> 3);
  const int e   = lid >> 8;
  const int rem = lid & 255;
  const int n0  = (rem >> 3) * BN;
  const int m0  = (rem & 7) * BM;
  const int tid = threadIdx.x;
  const int wave = tid >> 6, lane = tid & 63;
  const int wr = wave >> 1, wc = wave & 1;

  const int srow = lane >> 3;
  const int schunk = (lane & 7) ^ srow;
  const unsigned short* asrc[2];
  const unsigned short* bsrc[2];
#pragma unroll
  for (int j = 0; j < 2; j++) {
    const int r = wave * 16 + j * 8 + srow;
    const int tok = sel[e * ROWS + m0 + r];
    asrc[j] = xb + (size_t)tok * D_ + schunk * 8;
    bsrc[j] = w1t + ((size_t)e * F_ + n0 + r) * D_ + schunk * 8;
  }

  f32x4 acc[2][2];
#pragma unroll
  for (int mi = 0; mi < 2; mi++)
#pragma unroll
    for (int nj = 0; nj < 2; nj++) acc[mi][nj] = (f32x4){0.f, 0.f, 0.f, 0.f};

  const int fr = lane & 15;

  for (int t = 0; t < D_ / BK; t++) {
    const int k0 = t * BK;
#pragma unroll
    for (int j = 0; j < 2; j++) {
      gload16(&As[(wave * 16 + j * 8) * BK], asrc[j] + k0);
      gload16(&Bs[(wave * 16 + j * 8) * BK], bsrc[j] + k0);
    }
    __syncthreads();                 // staging complete (implicit vmcnt(0))
    bf16x8 a[2][2], b[2][2];
#pragma unroll
    for (int kk = 0; kk < 2; kk++) {
      const int xch = ((kk * 4 + (lane >> 4)) ^ (lane & 7)) * 8;
#pragma unroll
      for (int mi = 0; mi < 2; mi++)
        a[kk][mi] = *(const bf16x8*)&As[(wr * 32 + mi * 16 + fr) * BK + xch];
#pragma unroll
      for (int nj = 0; nj < 2; nj++)
        b[kk][nj] = *(const bf16x8*)&Bs[(wc * 32 + nj * 16 + fr) * BK + xch];
    }
#pragma unroll
    for (int kk = 0; kk < 2; kk++)
#pragma unroll
      for (int mi = 0; mi < 2; mi++)
#pragma unroll
        for (int nj = 0; nj < 2; nj++)
          acc[mi][nj] = __builtin_amdgcn_mfma_f32_16x16x32_bf16(a[kk][mi], b[kk][nj], acc[mi][nj], 0, 0, 0);
    __syncthreads();                 // all waves done reading before next overwrite
  }

  const int lr = (lane >> 4) * 4;
#pragma unroll
  for (int mi = 0; mi < 2; mi++)
#pragma unroll
    for (int nj = 0; nj < 2; nj++)
#pragma unroll
      for (int rg = 0; rg < 4; rg++) {
        const int row = m0 + wr * 32 + mi * 16 + lr + rg;
        const int col = n0 + wc * 32 + nj * 16 + fr;
        float v = acc[mi][nj][rg] + b1[e * F_ + col];
        v = 0.5f * v * (1.0f + erff(v * 0.70710678118654752f));   // exact GELU
        hbuf[((size_t)e * ROWS + row) * F_ + col] = f2bf(v);
      }
}

// ---------- row LayerNorm over F_, in place on bf16 h ----------
__global__ void ln_kernel(unsigned short* __restrict__ hbuf,
                          const float* __restrict__ g_ln, const float* __restrict__ b_ln) {
  const int row = blockIdx.x;          // 0..E_*ROWS-1
  const int e = row >> 9;
  unsigned short* hr = hbuf + (size_t)row * F_;
  const int tid = threadIdx.x;
  union { bf16x8 v; unsigned short u[8]; } u;
  u.v = *(const bf16x8*)&hr[tid * 8];
  float vals[8]; float s1 = 0.f, s2 = 0.f;
#pragma unroll
  for (int j = 0; j < 8; j++) { float f = bf2f(u.u[j]); vals[j] = f; s1 += f; s2 += f * f; }
#pragma unroll
  for (int off = 32; off; off >>= 1) { s1 += __shfl_down(s1, off); s2 += __shfl_down(s2, off); }
  __shared__ float rs[8];
  const int wave = tid >> 6, lane = tid & 63;
  if (lane == 0) { rs[wave] = s1; rs[wave + 4] = s2; }
  __syncthreads();
  const float t1 = rs[0] + rs[1] + rs[2] + rs[3];
  const float t2 = rs[4] + rs[5] + rs[6] + rs[7];
  const float mu = t1 * (1.f / F_);
  const float var = t2 * (1.f / F_) - mu * mu;   // biased var (jnp.var)
  const float rstd = rsqrtf(var + 1e-5f);
  const float4* gl4 = (const float4*)(g_ln + (size_t)e * F_ + tid * 8);
  const float4* bl4 = (const float4*)(b_ln + (size_t)e * F_ + tid * 8);
  float4 g0 = gl4[0], g1 = gl4[1], bb0 = bl4[0], bb1 = bl4[1];
  float gs[8] = {g0.x, g0.y, g0.z, g0.w, g1.x, g1.y, g1.z, g1.w};
  float bs[8] = {bb0.x, bb0.y, bb0.z, bb0.w, bb1.x, bb1.y, bb1.z, bb1.w};
  union { bf16x8 v; unsigned short u[8]; } o;
#pragma unroll
  for (int j = 0; j < 8; j++)
    o.u[j] = f2bf((vals[j] - mu) * rstd * gs[j] + bs[j]);
  *(bf16x8*)&hr[tid * 8] = o.v;
}

// ====================== GEMM2 partial: split-K x2, D1 structure, plain stores ======================
__global__ __launch_bounds__(256, 8) void gemm2_partial_kernel(
    const unsigned short* __restrict__ hbuf, // [E][ROWS][F_]
    const unsigned short* __restrict__ w2t,  // [E][O_][F_]
    float* __restrict__ part) {              // [2][E_*ROWS][O_]
  __shared__ unsigned short As[TILE_ELEMS];
  __shared__ unsigned short Bs[TILE_ELEMS];
  const int bid = blockIdx.x;
  const int lid = (bid & 7) * 256 + (bid >> 3);   // 8 XCDs x 256; expert-per-XCD
  const int e     = lid >> 8;
  const int rem   = lid & 255;
  const int khalf = rem & 1;
  const int m0    = ((rem >> 1) & 7) * BM;
  const int n0    = (rem >> 4) * BN;              // 16 O panels
  const int koff  = khalf * (F_ / 2);
  const int tid = threadIdx.x;
  const int wave = tid >> 6, lane = tid & 63;
  const int wr = wave >> 1, wc = wave & 1;

  const int srow = lane >> 3;
  const int schunk = (lane & 7) ^ srow;
  const unsigned short* asrc[2];
  const unsigned short* bsrc[2];
#pragma unroll
  for (int j = 0; j < 2; j++) {
    const int r = wave * 16 + j * 8 + srow;
    asrc[j] = hbuf + ((size_t)e * ROWS + m0 + r) * F_ + koff + schunk * 8;
    bsrc[j] = w2t + ((size_t)e * O_ + n0 + r) * F_ + koff + schunk * 8;
  }

  f32x4 acc[2][2];
#pragma unroll
  for (int mi = 0; mi < 2; mi++)
#pragma unroll
    for (int nj = 0; nj < 2; nj++) acc[mi][nj] = (f32x4){0.f, 0.f, 0.f, 0.f};

  const int fr = lane & 15;

  for (int t = 0; t < (F_ / 2) / BK; t++) {   // 16 steps
    const int k0 = t * BK;
#pragma unroll
    for (int j = 0; j < 2; j++) {
      gload16(&As[(wave * 16 + j * 8) * BK], asrc[j] + k0);
      gload16(&Bs[(wave * 16 + j * 8) * BK], bsrc[j] + k0);
    }
    __syncthreads();
    bf16x8 a[2][2], b[2][2];
#pragma unroll
    for (int kk = 0; kk < 2; kk++) {
      const int xch = ((kk * 4 + (lane >> 4)) ^ (lane & 7)) * 8;
#pragma unroll
      for (int mi = 0; mi < 2; mi++)
        a[kk][mi] = *(const bf16x8*)&As[(wr * 32 + mi * 16 + fr) * BK + xch];
#pragma unroll
      for (int nj = 0; nj < 2; nj++)
        b[kk][nj] = *(const bf16x8*)&Bs[(wc * 32 + nj * 16 + fr) * BK + xch];
    }
#pragma unroll
    for (int kk = 0; kk < 2; kk++)
#pragma unroll
      for (int mi = 0; mi < 2; mi++)
#pragma unroll
        for (int nj = 0; nj < 2; nj++)
          acc[mi][nj] = __builtin_amdgcn_mfma_f32_16x16x32_bf16(a[kk][mi], b[kk][nj], acc[mi][nj], 0, 0, 0);
    __syncthreads();
  }

  float* pbase = part + (size_t)khalf * (E_ * ROWS) * O_;
  const int lr = (lane >> 4) * 4;
#pragma unroll
  for (int mi = 0; mi < 2; mi++)
#pragma unroll
    for (int rg = 0; rg < 4; rg++) {
      const int row = m0 + wr * 32 + mi * 16 + lr + rg;
#pragma unroll
      for (int nj = 0; nj < 2; nj++) {
        const int col = n0 + wc * 32 + nj * 16 + fr;
        pbase[((size_t)(e * ROWS) + row) * O_ + col] = acc[mi][nj][rg];
      }
    }
}

// ---------- combine: out[tok] = sum_e gate * (p0 + p1 + b2[e]) ; atomic-free ----------
__global__ void combine_kernel(const float* __restrict__ part, const int* __restrict__ entry,
                               const float* __restrict__ gate, const float* __restrict__ b2,
                               float* __restrict__ out) {
  const int tok = blockIdx.x;
  const int c = threadIdx.x * 4;
  float4 acc = {0.f, 0.f, 0.f, 0.f};
#pragma unroll
  for (int e = 0; e < E_; e++) {
    const int r1 = entry[tok * E_ + e];
    if (r1) {
      const int idx = e * ROWS + (r1 - 1);
      const float g = gate[idx];
      const float4 p0 = *(const float4*)&part[(size_t)idx * O_ + c];
      const float4 p1 = *(const float4*)&part[(size_t)(E_ * ROWS + idx) * O_ + c];
      const float4 bb = *(const float4*)&b2[e * O_ + c];
      acc.x += g * (p0.x + p1.x + bb.x);
      acc.y += g * (p0.y + p1.y + bb.y);
      acc.z += g * (p0.z + p1.z + bb.z);
      acc.w += g * (p0.w + p1.w + bb.w);
    }
  }
  *(float4*)&out[(size_t)tok * O_ + c] = acc;
}

// ---------- launch ----------
extern "C" void kernel_launch(void* const* d_in, const int* in_sizes, int n_in,
                              void* d_out, int out_size, void* d_ws, size_t ws_size,
                              hipStream_t stream) {
  const float* x     = (const float*)d_in[0];
  const float* wg    = (const float*)d_in[1];
  const float* w1    = (const float*)d_in[2];
  const float* b1    = (const float*)d_in[3];
  const float* g_ln  = (const float*)d_in[4];
  const float* b_ln  = (const float*)d_in[5];
  const float* w2    = (const float*)d_in[6];
  const float* b2    = (const float*)d_in[7];
  float* out = (float*)d_out;
  float* out_logits = out + (size_t)NTOK * O_;

  char* wsb = (char*)d_ws;
  unsigned short* xb   = (unsigned short*)(wsb + 0);          // 8,388,608 B
  unsigned short* w1t  = (unsigned short*)(wsb + 8388608);    // 33,554,432 B (reused as part)
  unsigned short* w2t  = (unsigned short*)(wsb + 41943040);   // 33,554,432 B
  unsigned short* hbuf = (unsigned short*)(wsb + 75497472);   // 16,777,216 B
  float* probs = (float*)(wsb + 92274688);                    // 131,072 B
  int*   sel   = (int*)  (wsb + 92405760);                    // 16,384 B
  float* gate  = (float*)(wsb + 92422144);                    // 16,384 B
  int*   entry = (int*)  (wsb + 92438528);                    // 131,072 B
  float* part  = (float*)(wsb + 8388608);                     // aliases w1t (dead after gemm1)

  gating_kernel<<<NTOK / 4, 256, 0, stream>>>(x, wg, out_logits, probs, xb);
  transpose_cvt_kernel<<<dim3(F_ / 64, D_ / 64, E_), 256, 0, stream>>>(w1, w1t, D_, F_); // -> [F][D]
  transpose_cvt_kernel<<<dim3(O_ / 64, F_ / 64, E_), 256, 0, stream>>>(w2, w2t, F_, O_); // -> [O][F]
  topk_kernel<<<2 * E_ * 8, 256, 0, stream>>>(out_logits, probs, sel, gate, entry);
  gemm1_kernel<<<(F_ / BN) * (ROWS / BM) * E_, 256, 0, stream>>>(xb, w1t, b1, sel, hbuf);
  ln_kernel<<<E_ * ROWS, 256, 0, stream>>>(hbuf, g_ln, b_ln);
  gemm2_partial_kernel<<<2048, 256, 0, stream>>>(hbuf, w2t, part);
  combine_kernel<<<NTOK, 256, 0, stream>>>(part, entry, gate, b2, out);
}

// Round 14
// 149.923 us; speedup vs baseline: 1.2044x; 1.0002x over previous
//
#include <hip/hip_runtime.h>
#include <cstdint>
#include <cstddef>

typedef __attribute__((ext_vector_type(8))) short bf16x8;
typedef __attribute__((ext_vector_type(4))) float f32x4;

#define S_    2048
#define D_    1024
#define F_    2048
#define O_    1024
#define E_    8
#define KCAP  256
#define ROWS  512           // 2 batches * KCAP per expert
#define NTOK  4096          // B*S

#define BM 64
#define BN 64
#define BK 64
#define TILE_ELEMS (BM * BK)

// ---------- bf16 helpers ----------
__device__ __forceinline__ unsigned short f2bf(float f) {
  unsigned int u = __float_as_uint(f);
  u = (u + 0x7fffu + ((u >> 16) & 1u)) >> 16;   // RNE
  return (unsigned short)u;
}
__device__ __forceinline__ float bf2f(unsigned short h) {
  return __uint_as_float(((unsigned int)h) << 16);
}

// ---------- async global->LDS, 16B per lane, wave-uniform LDS base ----------
__device__ __forceinline__ void gload16(void* lds, const void* g) {
  auto gp = (__attribute__((address_space(1))) unsigned int*)(uintptr_t)g;
  auto lp = (__attribute__((address_space(3))) unsigned int*)(unsigned int)(uintptr_t)lds;
  __builtin_amdgcn_global_load_lds(gp, lp, 16, 0, 0);
}

// ---------- gating: logits (fp64 accum) + softmax probs + x->bf16 ----------
__global__ void gating_kernel(const float* __restrict__ x, const float* __restrict__ wg,
                              float* __restrict__ logits, float* __restrict__ probs,
                              unsigned short* __restrict__ xb) {
  const int wave = threadIdx.x >> 6, lane = threadIdx.x & 63;
  const int t = blockIdx.x * 4 + wave;
  const float* xr = x + (size_t)t * D_;
  double acc[8] = {0, 0, 0, 0, 0, 0, 0, 0};
  const int d0 = lane * 16;
#pragma unroll
  for (int i = 0; i < 4; i++) {
    float4 xv = *(const float4*)&xr[d0 + i * 4];
    union { ushort4 u4; unsigned short u[4]; } cv;
    cv.u[0] = f2bf(xv.x); cv.u[1] = f2bf(xv.y); cv.u[2] = f2bf(xv.z); cv.u[3] = f2bf(xv.w);
    *(ushort4*)&xb[(size_t)t * D_ + d0 + i * 4] = cv.u4;
    float xs[4] = {xv.x, xv.y, xv.z, xv.w};
#pragma unroll
    for (int j = 0; j < 4; j++) {
      const float4* wr = (const float4*)&wg[(size_t)(d0 + i * 4 + j) * 8];
      float4 w0 = wr[0], w1v = wr[1];
      double xd = (double)xs[j];
      acc[0] += xd * (double)w0.x;  acc[1] += xd * (double)w0.y;
      acc[2] += xd * (double)w0.z;  acc[3] += xd * (double)w0.w;
      acc[4] += xd * (double)w1v.x; acc[5] += xd * (double)w1v.y;
      acc[6] += xd * (double)w1v.z; acc[7] += xd * (double)w1v.w;
    }
  }
#pragma unroll
  for (int off = 32; off; off >>= 1) {
#pragma unroll
    for (int e = 0; e < 8; e++) acc[e] += __shfl_down(acc[e], off);
  }
  if (lane == 0) {
    double m = acc[0];
    for (int e = 1; e < 8; e++) m = acc[e] > m ? acc[e] : m;
    double p[8]; double s = 0;
    for (int e = 0; e < 8; e++) { p[e] = exp(acc[e] - m); s += p[e]; }
    const double inv = 1.0 / s;
    for (int e = 0; e < 8; e++) {
      logits[(size_t)t * 8 + e] = (float)acc[e];
      probs [(size_t)t * 8 + e] = (float)(p[e] * inv);
    }
  }
}

// ---------- merged transpose + fp32->bf16 for BOTH weights, 16B coalesced stores ----------
// blocks 0..4095: w1 ([D][F] per expert -> [F][D]); 4096..8191: w2 ([F][O] -> [O][F]).
__global__ void transpose_both_kernel(const float* __restrict__ w1, unsigned short* __restrict__ w1t,
                                      const float* __restrict__ w2, unsigned short* __restrict__ w2t) {
  __shared__ float t[64][65];
  const int bid = blockIdx.x;
  const bool isW2 = bid >= 4096;
  const int rem = bid & 4095;
  const int e = rem >> 9;              // 512 blocks per expert for both
  const int p = rem & 511;
  int R, C, r0, c0;
  const float* inp;
  unsigned short* outp;
  if (!isW2) {
    R = D_; C = F_;
    c0 = (p & 31) * 64; r0 = (p >> 5) * 64;   // 32 C-panels x 16 R-panels
    inp = w1 + (size_t)e * R * C;  outp = w1t + (size_t)e * R * C;
  } else {
    R = F_; C = O_;
    c0 = (p & 15) * 64; r0 = (p >> 4) * 64;   // 16 C-panels x 32 R-panels
    inp = w2 + (size_t)e * R * C;  outp = w2t + (size_t)e * R * C;
  }
  const int tid = threadIdx.x;
  const int lr = tid >> 4;          // 0..15
  const int lc = (tid & 15) * 4;    // 0..60
#pragma unroll
  for (int i = 0; i < 4; i++) {
    const int r = lr + i * 16;
    const float4 v = *(const float4*)&inp[(size_t)(r0 + r) * C + c0 + lc];
    t[r][lc] = v.x; t[r][lc + 1] = v.y; t[r][lc + 2] = v.z; t[r][lc + 3] = v.w;
  }
  __syncthreads();
  const int r8 = (tid & 7) * 8;
#pragma unroll
  for (int it = 0; it < 2; it++) {
    const int c = (tid >> 3) + it * 32;
    union { bf16x8 v; unsigned short u[8]; } o;
#pragma unroll
    for (int j = 0; j < 8; j++) o.u[j] = f2bf(t[r8 + j][c]);
    *(bf16x8*)&outp[(size_t)(c0 + c) * R + r0 + r8] = o.v;
  }
}

// ---------- expert-choice top-k + deterministic per-token inverse index ----------
__global__ void topk_kernel(const float* __restrict__ logits, const float* __restrict__ probs,
                            int* __restrict__ sel, float* __restrict__ gate,
                            int* __restrict__ entry) {    // entry[tok][e] = row+1 (0 = absent)
  __shared__ unsigned int keys[S_];
  const int idx = blockIdx.x;       // 0..127 : (b,e) x 8 segments
  const int seg = idx & 7;
  const int be = idx >> 3;          // 0..15
  const int b = be >> 3;            // 0..1
  const int e = be & 7;
  const int tid = threadIdx.x;
  for (int i = tid; i < S_; i += 256) {
    unsigned int u = __float_as_uint(logits[((size_t)(b * S_ + i)) * E_ + e]);
    keys[i] = u ^ ((u & 0x80000000u) ? 0xFFFFFFFFu : 0x80000000u);
  }
  __syncthreads();
  const int s = seg * 256 + tid;
  const unsigned int vk = keys[s];
  const int wave = tid >> 6;
  const int W0 = seg * 256 + wave * 64;
  int rank = 0;
#pragma unroll 4
  for (int i = 0; i < W0; i += 4) {
    const uint4 kv = *(const uint4*)&keys[i];
    rank += (kv.x >= vk) + (kv.y >= vk) + (kv.z >= vk) + (kv.w >= vk);
  }
#pragma unroll
  for (int j = 0; j < 64; j++) {
    const int i = W0 + j;
    const unsigned int kv = keys[i];
    rank += (kv > vk) || (kv == vk && i < s);
  }
#pragma unroll 4
  for (int i = W0 + 64; i < S_; i += 4) {
    const uint4 kv = *(const uint4*)&keys[i];
    rank += (kv.x > vk) + (kv.y > vk) + (kv.z > vk) + (kv.w > vk);
  }
  const int tok = b * S_ + s;
  if (rank < KCAP) {
    const int row = b * KCAP + rank;
    sel  [e * ROWS + row] = tok;
    gate [e * ROWS + row] = probs[(size_t)tok * E_ + e];
    entry[tok * E_ + e]   = row + 1;
  } else {
    entry[tok * E_ + e]   = 0;
  }
}

// ====================== GEMM1 (D1): single-buffer, 8 blocks/CU ======================
__global__ __launch_bounds__(256, 8) void gemm1_kernel(
    const unsigned short* __restrict__ xb, const unsigned short* __restrict__ w1t,
    const float* __restrict__ b1, const int* __restrict__ sel,
    unsigned short* __restrict__ hbuf) {
  __shared__ unsigned short As[TILE_ELEMS];   // 8 KB
  __shared__ unsigned short Bs[TILE_ELEMS];   // 8 KB
  const int bid = blockIdx.x;
  const int lid = (bid & 7) * 256 + (bid >> 3);
  const int e   = lid >> 8;
  const int rem = lid & 255;
  const int n0  = (rem >> 3) * BN;
  const int m0  = (rem & 7) * BM;
  const int tid = threadIdx.x;
  const int wave = tid >> 6, lane = tid & 63;
  const int wr = wave >> 1, wc = wave & 1;

  const int srow = lane >> 3;
  const int schunk = (lane & 7) ^ srow;
  const unsigned short* asrc[2];
  const unsigned short* bsrc[2];
#pragma unroll
  for (int j = 0; j < 2; j++) {
    const int r = wave * 16 + j * 8 + srow;
    const int tok = sel[e * ROWS + m0 + r];
    asrc[j] = xb + (size_t)tok * D_ + schunk * 8;
    bsrc[j] = w1t + ((size_t)e * F_ + n0 + r) * D_ + schunk * 8;
  }

  f32x4 acc[2][2];
#pragma unroll
  for (int mi = 0; mi < 2; mi++)
#pragma unroll
    for (int nj = 0; nj < 2; nj++) acc[mi][nj] = (f32x4){0.f, 0.f, 0.f, 0.f};

  const int fr = lane & 15;

  for (int t = 0; t < D_ / BK; t++) {
    const int k0 = t * BK;
#pragma unroll
    for (int j = 0; j < 2; j++) {
      gload16(&As[(wave * 16 + j * 8) * BK], asrc[j] + k0);
      gload16(&Bs[(wave * 16 + j * 8) * BK], bsrc[j] + k0);
    }
    __syncthreads();                 // staging complete (implicit vmcnt(0))
    bf16x8 a[2][2], b[2][2];
#pragma unroll
    for (int kk = 0; kk < 2; kk++) {
      const int xch = ((kk * 4 + (lane >> 4)) ^ (lane & 7)) * 8;
#pragma unroll
      for (int mi = 0; mi < 2; mi++)
        a[kk][mi] = *(const bf16x8*)&As[(wr * 32 + mi * 16 + fr) * BK + xch];
#pragma unroll
      for (int nj = 0; nj < 2; nj++)
        b[kk][nj] = *(const bf16x8*)&Bs[(wc * 32 + nj * 16 + fr) * BK + xch];
    }
#pragma unroll
    for (int kk = 0; kk < 2; kk++)
#pragma unroll
      for (int mi = 0; mi < 2; mi++)
#pragma unroll
        for (int nj = 0; nj < 2; nj++)
          acc[mi][nj] = __builtin_amdgcn_mfma_f32_16x16x32_bf16(a[kk][mi], b[kk][nj], acc[mi][nj], 0, 0, 0);
    __syncthreads();                 // all waves done reading before next overwrite
  }

  const int lr = (lane >> 4) * 4;
#pragma unroll
  for (int mi = 0; mi < 2; mi++)
#pragma unroll
    for (int nj = 0; nj < 2; nj++)
#pragma unroll
      for (int rg = 0; rg < 4; rg++) {
        const int row = m0 + wr * 32 + mi * 16 + lr + rg;
        const int col = n0 + wc * 32 + nj * 16 + fr;
        float v = acc[mi][nj][rg] + b1[e * F_ + col];
        v = 0.5f * v * (1.0f + erff(v * 0.70710678118654752f));   // exact GELU
        hbuf[((size_t)e * ROWS + row) * F_ + col] = f2bf(v);
      }
}

// ---------- row LayerNorm over F_, in place on bf16 h ----------
__global__ void ln_kernel(unsigned short* __restrict__ hbuf,
                          const float* __restrict__ g_ln, const float* __restrict__ b_ln) {
  const int row = blockIdx.x;          // 0..E_*ROWS-1
  const int e = row >> 9;
  unsigned short* hr = hbuf + (size_t)row * F_;
  const int tid = threadIdx.x;
  union { bf16x8 v; unsigned short u[8]; } u;
  u.v = *(const bf16x8*)&hr[tid * 8];
  float vals[8]; float s1 = 0.f, s2 = 0.f;
#pragma unroll
  for (int j = 0; j < 8; j++) { float f = bf2f(u.u[j]); vals[j] = f; s1 += f; s2 += f * f; }
#pragma unroll
  for (int off = 32; off; off >>= 1) { s1 += __shfl_down(s1, off); s2 += __shfl_down(s2, off); }
  __shared__ float rs[8];
  const int wave = tid >> 6, lane = tid & 63;
  if (lane == 0) { rs[wave] = s1; rs[wave + 4] = s2; }
  __syncthreads();
  const float t1 = rs[0] + rs[1] + rs[2] + rs[3];
  const float t2 = rs[4] + rs[5] + rs[6] + rs[7];
  const float mu = t1 * (1.f / F_);
  const float var = t2 * (1.f / F_) - mu * mu;   // biased var (jnp.var)
  const float rstd = rsqrtf(var + 1e-5f);
  const float4* gl4 = (const float4*)(g_ln + (size_t)e * F_ + tid * 8);
  const float4* bl4 = (const float4*)(b_ln + (size_t)e * F_ + tid * 8);
  float4 g0 = gl4[0], g1 = gl4[1], bb0 = bl4[0], bb1 = bl4[1];
  float gs[8] = {g0.x, g0.y, g0.z, g0.w, g1.x, g1.y, g1.z, g1.w};
  float bs[8] = {bb0.x, bb0.y, bb0.z, bb0.w, bb1.x, bb1.y, bb1.z, bb1.w};
  union { bf16x8 v; unsigned short u[8]; } o;
#pragma unroll
  for (int j = 0; j < 8; j++)
    o.u[j] = f2bf((vals[j] - mu) * rstd * gs[j] + bs[j]);
  *(bf16x8*)&hr[tid * 8] = o.v;
}

// ====================== GEMM2 partial: split-K x2, D1 structure, plain stores ======================
__global__ __launch_bounds__(256, 8) void gemm2_partial_kernel(
    const unsigned short* __restrict__ hbuf, // [E][ROWS][F_]
    const unsigned short* __restrict__ w2t,  // [E][O_][F_]
    float* __restrict__ part) {              // [2][E_*ROWS][O_]
  __shared__ unsigned short As[TILE_ELEMS];
  __shared__ unsigned short Bs[TILE_ELEMS];
  const int bid = blockIdx.x;
  const int lid = (bid & 7) * 256 + (bid >> 3);   // 8 XCDs x 256; expert-per-XCD
  const int e     = lid >> 8;
  const int rem   = lid & 255;
  const int khalf = rem & 1;
  const int m0    = ((rem >> 1) & 7) * BM;
  const int n0    = (rem >> 4) * BN;              // 16 O panels
  const int koff  = khalf * (F_ / 2);
  const int tid = threadIdx.x;
  const int wave = tid >> 6, lane = tid & 63;
  const int wr = wave >> 1, wc = wave & 1;

  const int srow = lane >> 3;
  const int schunk = (lane & 7) ^ srow;
  const unsigned short* asrc[2];
  const unsigned short* bsrc[2];
#pragma unroll
  for (int j = 0; j < 2; j++) {
    const int r = wave * 16 + j * 8 + srow;
    asrc[j] = hbuf + ((size_t)e * ROWS + m0 + r) * F_ + koff + schunk * 8;
    bsrc[j] = w2t + ((size_t)e * O_ + n0 + r) * F_ + koff + schunk * 8;
  }

  f32x4 acc[2][2];
#pragma unroll
  for (int mi = 0; mi < 2; mi++)
#pragma unroll
    for (int nj = 0; nj < 2; nj++) acc[mi][nj] = (f32x4){0.f, 0.f, 0.f, 0.f};

  const int fr = lane & 15;

  for (int t = 0; t < (F_ / 2) / BK; t++) {   // 16 steps
    const int k0 = t * BK;
#pragma unroll
    for (int j = 0; j < 2; j++) {
      gload16(&As[(wave * 16 + j * 8) * BK], asrc[j] + k0);
      gload16(&Bs[(wave * 16 + j * 8) * BK], bsrc[j] + k0);
    }
    __syncthreads();
    bf16x8 a[2][2], b[2][2];
#pragma unroll
    for (int kk = 0; kk < 2; kk++) {
      const int xch = ((kk * 4 + (lane >> 4)) ^ (lane & 7)) * 8;
#pragma unroll
      for (int mi = 0; mi < 2; mi++)
        a[kk][mi] = *(const bf16x8*)&As[(wr * 32 + mi * 16 + fr) * BK + xch];
#pragma unroll
      for (int nj = 0; nj < 2; nj++)
        b[kk][nj] = *(const bf16x8*)&Bs[(wc * 32 + nj * 16 + fr) * BK + xch];
    }
#pragma unroll
    for (int kk = 0; kk < 2; kk++)
#pragma unroll
      for (int mi = 0; mi < 2; mi++)
#pragma unroll
        for (int nj = 0; nj < 2; nj++)
          acc[mi][nj] = __builtin_amdgcn_mfma_f32_16x16x32_bf16(a[kk][mi], b[kk][nj], acc[mi][nj], 0, 0, 0);
    __syncthreads();
  }

  float* pbase = part + (size_t)khalf * (E_ * ROWS) * O_;
  const int lr = (lane >> 4) * 4;
#pragma unroll
  for (int mi = 0; mi < 2; mi++)
#pragma unroll
    for (int rg = 0; rg < 4; rg++) {
      const int row = m0 + wr * 32 + mi * 16 + lr + rg;
#pragma unroll
      for (int nj = 0; nj < 2; nj++) {
        const int col = n0 + wc * 32 + nj * 16 + fr;
        pbase[((size_t)(e * ROWS) + row) * O_ + col] = acc[mi][nj][rg];
      }
    }
}

// ---------- combine: out[tok] = sum_e gate * (p0 + p1 + b2[e]) ; atomic-free ----------
__global__ void combine_kernel(const float* __restrict__ part, const int* __restrict__ entry,
                               const float* __restrict__ gate, const float* __restrict__ b2,
                               float* __restrict__ out) {
  const int tok = blockIdx.x;
  const int c = threadIdx.x * 4;
  float4 acc = {0.f, 0.f, 0.f, 0.f};
#pragma unroll
  for (int e = 0; e < E_; e++) {
    const int r1 = entry[tok * E_ + e];
    if (r1) {
      const int idx = e * ROWS + (r1 - 1);
      const float g = gate[idx];
      const float4 p0 = *(const float4*)&part[(size_t)idx * O_ + c];
      const float4 p1 = *(const float4*)&part[(size_t)(E_ * ROWS + idx) * O_ + c];
      const float4 bb = *(const float4*)&b2[e * O_ + c];
      acc.x += g * (p0.x + p1.x + bb.x);
      acc.y += g * (p0.y + p1.y + bb.y);
      acc.z += g * (p0.z + p1.z + bb.z);
      acc.w += g * (p0.w + p1.w + bb.w);
    }
  }
  *(float4*)&out[(size_t)tok * O_ + c] = acc;
}

// ---------- launch ----------
extern "C" void kernel_launch(void* const* d_in, const int* in_sizes, int n_in,
                              void* d_out, int out_size, void* d_ws, size_t ws_size,
                              hipStream_t stream) {
  const float* x     = (const float*)d_in[0];
  const float* wg    = (const float*)d_in[1];
  const float* w1    = (const float*)d_in[2];
  const float* b1    = (const float*)d_in[3];
  const float* g_ln  = (const float*)d_in[4];
  const float* b_ln  = (const float*)d_in[5];
  const float* w2    = (const float*)d_in[6];
  const float* b2    = (const float*)d_in[7];
  float* out = (float*)d_out;
  float* out_logits = out + (size_t)NTOK * O_;

  char* wsb = (char*)d_ws;
  unsigned short* xb   = (unsigned short*)(wsb + 0);          // 8,388,608 B
  unsigned short* w1t  = (unsigned short*)(wsb + 8388608);    // 33,554,432 B (reused as part)
  unsigned short* w2t  = (unsigned short*)(wsb + 41943040);   // 33,554,432 B
  unsigned short* hbuf = (unsigned short*)(wsb + 75497472);   // 16,777,216 B
  float* probs = (float*)(wsb + 92274688);                    // 131,072 B
  int*   sel   = (int*)  (wsb + 92405760);                    // 16,384 B
  float* gate  = (float*)(wsb + 92422144);                    // 16,384 B
  int*   entry = (int*)  (wsb + 92438528);                    // 131,072 B
  float* part  = (float*)(wsb + 8388608);                     // aliases w1t (dead after gemm1)

  gating_kernel<<<NTOK / 4, 256, 0, stream>>>(x, wg, out_logits, probs, xb);
  transpose_both_kernel<<<8192, 256, 0, stream>>>(w1, w1t, w2, w2t);
  topk_kernel<<<2 * E_ * 8, 256, 0, stream>>>(out_logits, probs, sel, gate, entry);
  gemm1_kernel<<<(F_ / BN) * (ROWS / BM) * E_, 256, 0, stream>>>(xb, w1t, b1, sel, hbuf);
  ln_kernel<<<E_ * ROWS, 256, 0, stream>>>(hbuf, g_ln, b_ln);
  gemm2_partial_kernel<<<2048, 256, 0, stream>>>(hbuf, w2t, part);
  combine_kernel<<<NTOK, 256, 0, stream>>>(part, entry, gate, b2, out);
}

// Round 15
// 149.654 us; speedup vs baseline: 1.2065x; 1.0018x over previous
//
#include <hip/hip_runtime.h>
#include <cstdint>
#include <cstddef>

typedef __attribute__((ext_vector_type(8))) short bf16x8;
typedef __attribute__((ext_vector_type(4))) float f32x4;

#define S_    2048
#define D_    1024
#define F_    2048
#define O_    1024
#define E_    8
#define KCAP  256
#define ROWS  512           // 2 batches * KCAP per expert
#define NTOK  4096          // B*S

#define BM 64
#define BN 64
#define BK 64
#define TILE_ELEMS (BM * BK)

// ---------- bf16 helpers ----------
__device__ __forceinline__ unsigned short f2bf(float f) {
  unsigned int u = __float_as_uint(f);
  u = (u + 0x7fffu + ((u >> 16) & 1u)) >> 16;   // RNE
  return (unsigned short)u;
}
__device__ __forceinline__ float bf2f(unsigned short h) {
  return __uint_as_float(((unsigned int)h) << 16);
}

// ---------- async global->LDS, 16B per lane, wave-uniform LDS base ----------
__device__ __forceinline__ void gload16(void* lds, const void* g) {
  auto gp = (__attribute__((address_space(1))) unsigned int*)(uintptr_t)g;
  auto lp = (__attribute__((address_space(3))) unsigned int*)(unsigned int)(uintptr_t)lds;
  __builtin_amdgcn_global_load_lds(gp, lp, 16, 0, 0);
}

// ---------- gating: logits (fp64 accum) + softmax probs + x->bf16 ----------
__global__ void gating_kernel(const float* __restrict__ x, const float* __restrict__ wg,
                              float* __restrict__ logits, float* __restrict__ probs,
                              unsigned short* __restrict__ xb) {
  const int wave = threadIdx.x >> 6, lane = threadIdx.x & 63;
  const int t = blockIdx.x * 4 + wave;
  const float* xr = x + (size_t)t * D_;
  double acc[8] = {0, 0, 0, 0, 0, 0, 0, 0};
  const int d0 = lane * 16;
#pragma unroll
  for (int i = 0; i < 4; i++) {
    float4 xv = *(const float4*)&xr[d0 + i * 4];
    union { ushort4 u4; unsigned short u[4]; } cv;
    cv.u[0] = f2bf(xv.x); cv.u[1] = f2bf(xv.y); cv.u[2] = f2bf(xv.z); cv.u[3] = f2bf(xv.w);
    *(ushort4*)&xb[(size_t)t * D_ + d0 + i * 4] = cv.u4;
    float xs[4] = {xv.x, xv.y, xv.z, xv.w};
#pragma unroll
    for (int j = 0; j < 4; j++) {
      const float4* wr = (const float4*)&wg[(size_t)(d0 + i * 4 + j) * 8];
      float4 w0 = wr[0], w1v = wr[1];
      double xd = (double)xs[j];
      acc[0] += xd * (double)w0.x;  acc[1] += xd * (double)w0.y;
      acc[2] += xd * (double)w0.z;  acc[3] += xd * (double)w0.w;
      acc[4] += xd * (double)w1v.x; acc[5] += xd * (double)w1v.y;
      acc[6] += xd * (double)w1v.z; acc[7] += xd * (double)w1v.w;
    }
  }
#pragma unroll
  for (int off = 32; off; off >>= 1) {
#pragma unroll
    for (int e = 0; e < 8; e++) acc[e] += __shfl_down(acc[e], off);
  }
  if (lane == 0) {
    double m = acc[0];
    for (int e = 1; e < 8; e++) m = acc[e] > m ? acc[e] : m;
    double p[8]; double s = 0;
    for (int e = 0; e < 8; e++) { p[e] = exp(acc[e] - m); s += p[e]; }
    const double inv = 1.0 / s;
    for (int e = 0; e < 8; e++) {
      logits[(size_t)t * 8 + e] = (float)acc[e];
      probs [(size_t)t * 8 + e] = (float)(p[e] * inv);
    }
  }
}

// ---------- merged transpose + fp32->bf16, 4 tiles/block, reg-prefetch pipeline ----------
// 2048 blocks; block b handles tiles {b, b+2048, b+4096, b+6144}.
// Tiles 0..4095: w1 ([D][F] -> [F][D]); 4096..8191: w2 ([F][O] -> [O][F]).
// All 16 global loads issued up front -> HBM latency paid once per block, the
// four LDS-transpose/store phases then run back-to-back from registers.
__global__ void transpose_both_kernel(const float* __restrict__ w1, unsigned short* __restrict__ w1t,
                                      const float* __restrict__ w2, unsigned short* __restrict__ w2t) {
  __shared__ float t[64][65];
  const int tid = threadIdx.x;
  const int lr = tid >> 4;          // 0..15
  const int lc = (tid & 15) * 4;    // 0..60
  const int r8 = (tid & 7) * 8;

  const float* inp[4]; unsigned short* outp[4]; int Rv[4], Cv[4], r0v[4], c0v[4];
#pragma unroll
  for (int k = 0; k < 4; k++) {
    const int tile = blockIdx.x + k * 2048;
    const bool isW2 = tile >= 4096;
    const int rem = tile & 4095;
    const int e = rem >> 9;
    const int p = rem & 511;
    if (!isW2) {
      Rv[k] = D_; Cv[k] = F_;
      c0v[k] = (p & 31) * 64; r0v[k] = (p >> 5) * 64;
      inp[k] = w1 + (size_t)e * D_ * F_;  outp[k] = w1t + (size_t)e * D_ * F_;
    } else {
      Rv[k] = F_; Cv[k] = O_;
      c0v[k] = (p & 15) * 64; r0v[k] = (p >> 4) * 64;
      inp[k] = w2 + (size_t)e * F_ * O_;  outp[k] = w2t + (size_t)e * F_ * O_;
    }
  }

  // issue ALL loads up front (64 VGPR of payload)
  float4 v[4][4];
#pragma unroll
  for (int k = 0; k < 4; k++)
#pragma unroll
    for (int i = 0; i < 4; i++)
      v[k][i] = *(const float4*)&inp[k][(size_t)(r0v[k] + lr + i * 16) * Cv[k] + c0v[k] + lc];

#pragma unroll
  for (int k = 0; k < 4; k++) {
#pragma unroll
    for (int i = 0; i < 4; i++) {
      const int r = lr + i * 16;
      t[r][lc] = v[k][i].x; t[r][lc + 1] = v[k][i].y; t[r][lc + 2] = v[k][i].z; t[r][lc + 3] = v[k][i].w;
    }
    __syncthreads();
#pragma unroll
    for (int it = 0; it < 2; it++) {
      const int c = (tid >> 3) + it * 32;
      union { bf16x8 vv; unsigned short u[8]; } o;
#pragma unroll
      for (int j = 0; j < 8; j++) o.u[j] = f2bf(t[r8 + j][c]);
      *(bf16x8*)&outp[k][(size_t)(c0v[k] + c) * Rv[k] + r0v[k] + r8] = o.vv;
    }
    __syncthreads();   // all reads of t done before next tile overwrites
  }
}

// ---------- expert-choice top-k + deterministic per-token inverse index ----------
__global__ void topk_kernel(const float* __restrict__ logits, const float* __restrict__ probs,
                            int* __restrict__ sel, float* __restrict__ gate,
                            int* __restrict__ entry) {    // entry[tok][e] = row+1 (0 = absent)
  __shared__ unsigned int keys[S_];
  const int idx = blockIdx.x;       // 0..127 : (b,e) x 8 segments
  const int seg = idx & 7;
  const int be = idx >> 3;          // 0..15
  const int b = be >> 3;            // 0..1
  const int e = be & 7;
  const int tid = threadIdx.x;
  for (int i = tid; i < S_; i += 256) {
    unsigned int u = __float_as_uint(logits[((size_t)(b * S_ + i)) * E_ + e]);
    keys[i] = u ^ ((u & 0x80000000u) ? 0xFFFFFFFFu : 0x80000000u);
  }
  __syncthreads();
  const int s = seg * 256 + tid;
  const unsigned int vk = keys[s];
  const int wave = tid >> 6;
  const int W0 = seg * 256 + wave * 64;
  int rank = 0;
#pragma unroll 4
  for (int i = 0; i < W0; i += 4) {
    const uint4 kv = *(const uint4*)&keys[i];
    rank += (kv.x >= vk) + (kv.y >= vk) + (kv.z >= vk) + (kv.w >= vk);
  }
#pragma unroll
  for (int j = 0; j < 64; j++) {
    const int i = W0 + j;
    const unsigned int kv = keys[i];
    rank += (kv > vk) || (kv == vk && i < s);
  }
#pragma unroll 4
  for (int i = W0 + 64; i < S_; i += 4) {
    const uint4 kv = *(const uint4*)&keys[i];
    rank += (kv.x > vk) + (kv.y > vk) + (kv.z > vk) + (kv.w > vk);
  }
  const int tok = b * S_ + s;
  if (rank < KCAP) {
    const int row = b * KCAP + rank;
    sel  [e * ROWS + row] = tok;
    gate [e * ROWS + row] = probs[(size_t)tok * E_ + e];
    entry[tok * E_ + e]   = row + 1;
  } else {
    entry[tok * E_ + e]   = 0;
  }
}

// ====================== GEMM1 (D1): single-buffer, 8 blocks/CU ======================
__global__ __launch_bounds__(256, 8) void gemm1_kernel(
    const unsigned short* __restrict__ xb, const unsigned short* __restrict__ w1t,
    const float* __restrict__ b1, const int* __restrict__ sel,
    unsigned short* __restrict__ hbuf) {
  __shared__ unsigned short As[TILE_ELEMS];   // 8 KB
  __shared__ unsigned short Bs[TILE_ELEMS];   // 8 KB
  const int bid = blockIdx.x;
  const int lid = (bid & 7) * 256 + (bid >> 3);
  const int e   = lid >> 8;
  const int rem = lid & 255;
  const int n0  = (rem >> 3) * BN;
  const int m0  = (rem & 7) * BM;
  const int tid = threadIdx.x;
  const int wave = tid >> 6, lane = tid & 63;
  const int wr = wave >> 1, wc = wave & 1;

  const int srow = lane >> 3;
  const int schunk = (lane & 7) ^ srow;
  const unsigned short* asrc[2];
  const unsigned short* bsrc[2];
#pragma unroll
  for (int j = 0; j < 2; j++) {
    const int r = wave * 16 + j * 8 + srow;
    const int tok = sel[e * ROWS + m0 + r];
    asrc[j] = xb + (size_t)tok * D_ + schunk * 8;
    bsrc[j] = w1t + ((size_t)e * F_ + n0 + r) * D_ + schunk * 8;
  }

  f32x4 acc[2][2];
#pragma unroll
  for (int mi = 0; mi < 2; mi++)
#pragma unroll
    for (int nj = 0; nj < 2; nj++) acc[mi][nj] = (f32x4){0.f, 0.f, 0.f, 0.f};

  const int fr = lane & 15;

  for (int t = 0; t < D_ / BK; t++) {
    const int k0 = t * BK;
#pragma unroll
    for (int j = 0; j < 2; j++) {
      gload16(&As[(wave * 16 + j * 8) * BK], asrc[j] + k0);
      gload16(&Bs[(wave * 16 + j * 8) * BK], bsrc[j] + k0);
    }
    __syncthreads();                 // staging complete (implicit vmcnt(0))
    bf16x8 a[2][2], b[2][2];
#pragma unroll
    for (int kk = 0; kk < 2; kk++) {
      const int xch = ((kk * 4 + (lane >> 4)) ^ (lane & 7)) * 8;
#pragma unroll
      for (int mi = 0; mi < 2; mi++)
        a[kk][mi] = *(const bf16x8*)&As[(wr * 32 + mi * 16 + fr) * BK + xch];
#pragma unroll
      for (int nj = 0; nj < 2; nj++)
        b[kk][nj] = *(const bf16x8*)&Bs[(wc * 32 + nj * 16 + fr) * BK + xch];
    }
#pragma unroll
    for (int kk = 0; kk < 2; kk++)
#pragma unroll
      for (int mi = 0; mi < 2; mi++)
#pragma unroll
        for (int nj = 0; nj < 2; nj++)
          acc[mi][nj] = __builtin_amdgcn_mfma_f32_16x16x32_bf16(a[kk][mi], b[kk][nj], acc[mi][nj], 0, 0, 0);
    __syncthreads();                 // all waves done reading before next overwrite
  }

  const int lr = (lane >> 4) * 4;
#pragma unroll
  for (int mi = 0; mi < 2; mi++)
#pragma unroll
    for (int nj = 0; nj < 2; nj++)
#pragma unroll
      for (int rg = 0; rg < 4; rg++) {
        const int row = m0 + wr * 32 + mi * 16 + lr + rg;
        const int col = n0 + wc * 32 + nj * 16 + fr;
        float v = acc[mi][nj][rg] + b1[e * F_ + col];
        v = 0.5f * v * (1.0f + erff(v * 0.70710678118654752f));   // exact GELU
        hbuf[((size_t)e * ROWS + row) * F_ + col] = f2bf(v);
      }
}

// ---------- row LayerNorm over F_, in place on bf16 h ----------
__global__ void ln_kernel(unsigned short* __restrict__ hbuf,
                          const float* __restrict__ g_ln, const float* __restrict__ b_ln) {
  const int row = blockIdx.x;          // 0..E_*ROWS-1
  const int e = row >> 9;
  unsigned short* hr = hbuf + (size_t)row * F_;
  const int tid = threadIdx.x;
  union { bf16x8 v; unsigned short u[8]; } u;
  u.v = *(const bf16x8*)&hr[tid * 8];
  float vals[8]; float s1 = 0.f, s2 = 0.f;
#pragma unroll
  for (int j = 0; j < 8; j++) { float f = bf2f(u.u[j]); vals[j] = f; s1 += f; s2 += f * f; }
#pragma unroll
  for (int off = 32; off; off >>= 1) { s1 += __shfl_down(s1, off); s2 += __shfl_down(s2, off); }
  __shared__ float rs[8];
  const int wave = tid >> 6, lane = tid & 63;
  if (lane == 0) { rs[wave] = s1; rs[wave + 4] = s2; }
  __syncthreads();
  const float t1 = rs[0] + rs[1] + rs[2] + rs[3];
  const float t2 = rs[4] + rs[5] + rs[6] + rs[7];
  const float mu = t1 * (1.f / F_);
  const float var = t2 * (1.f / F_) - mu * mu;   // biased var (jnp.var)
  const float rstd = rsqrtf(var + 1e-5f);
  const float4* gl4 = (const float4*)(g_ln + (size_t)e * F_ + tid * 8);
  const float4* bl4 = (const float4*)(b_ln + (size_t)e * F_ + tid * 8);
  float4 g0 = gl4[0], g1 = gl4[1], bb0 = bl4[0], bb1 = bl4[1];
  float gs[8] = {g0.x, g0.y, g0.z, g0.w, g1.x, g1.y, g1.z, g1.w};
  float bs[8] = {bb0.x, bb0.y, bb0.z, bb0.w, bb1.x, bb1.y, bb1.z, bb1.w};
  union { bf16x8 v; unsigned short u[8]; } o;
#pragma unroll
  for (int j = 0; j < 8; j++)
    o.u[j] = f2bf((vals[j] - mu) * rstd * gs[j] + bs[j]);
  *(bf16x8*)&hr[tid * 8] = o.v;
}

// ====================== GEMM2 partial: split-K x2, D1 structure, plain stores ======================
__global__ __launch_bounds__(256, 8) void gemm2_partial_kernel(
    const unsigned short* __restrict__ hbuf, // [E][ROWS][F_]
    const unsigned short* __restrict__ w2t,  // [E][O_][F_]
    float* __restrict__ part) {              // [2][E_*ROWS][O_]
  __shared__ unsigned short As[TILE_ELEMS];
  __shared__ unsigned short Bs[TILE_ELEMS];
  const int bid = blockIdx.x;
  const int lid = (bid & 7) * 256 + (bid >> 3);   // 8 XCDs x 256; expert-per-XCD
  const int e     = lid >> 8;
  const int rem   = lid & 255;
  const int khalf = rem & 1;
  const int m0    = ((rem >> 1) & 7) * BM;
  const int n0    = (rem >> 4) * BN;              // 16 O panels
  const int koff  = khalf * (F_ / 2);
  const int tid = threadIdx.x;
  const int wave = tid >> 6, lane = tid & 63;
  const int wr = wave >> 1, wc = wave & 1;

  const int srow = lane >> 3;
  const int schunk = (lane & 7) ^ srow;
  const unsigned short* asrc[2];
  const unsigned short* bsrc[2];
#pragma unroll
  for (int j = 0; j < 2; j++) {
    const int r = wave * 16 + j * 8 + srow;
    asrc[j] = hbuf + ((size_t)e * ROWS + m0 + r) * F_ + koff + schunk * 8;
    bsrc[j] = w2t + ((size_t)e * O_ + n0 + r) * F_ + koff + schunk * 8;
  }

  f32x4 acc[2][2];
#pragma unroll
  for (int mi = 0; mi < 2; mi++)
#pragma unroll
    for (int nj = 0; nj < 2; nj++) acc[mi][nj] = (f32x4){0.f, 0.f, 0.f, 0.f};

  const int fr = lane & 15;

  for (int t = 0; t < (F_ / 2) / BK; t++) {   // 16 steps
    const int k0 = t * BK;
#pragma unroll
    for (int j = 0; j < 2; j++) {
      gload16(&As[(wave * 16 + j * 8) * BK], asrc[j] + k0);
      gload16(&Bs[(wave * 16 + j * 8) * BK], bsrc[j] + k0);
    }
    __syncthreads();
    bf16x8 a[2][2], b[2][2];
#pragma unroll
    for (int kk = 0; kk < 2; kk++) {
      const int xch = ((kk * 4 + (lane >> 4)) ^ (lane & 7)) * 8;
#pragma unroll
      for (int mi = 0; mi < 2; mi++)
        a[kk][mi] = *(const bf16x8*)&As[(wr * 32 + mi * 16 + fr) * BK + xch];
#pragma unroll
      for (int nj = 0; nj < 2; nj++)
        b[kk][nj] = *(const bf16x8*)&Bs[(wc * 32 + nj * 16 + fr) * BK + xch];
    }
#pragma unroll
    for (int kk = 0; kk < 2; kk++)
#pragma unroll
      for (int mi = 0; mi < 2; mi++)
#pragma unroll
        for (int nj = 0; nj < 2; nj++)
          acc[mi][nj] = __builtin_amdgcn_mfma_f32_16x16x32_bf16(a[kk][mi], b[kk][nj], acc[mi][nj], 0, 0, 0);
    __syncthreads();
  }

  float* pbase = part + (size_t)khalf * (E_ * ROWS) * O_;
  const int lr = (lane >> 4) * 4;
#pragma unroll
  for (int mi = 0; mi < 2; mi++)
#pragma unroll
    for (int rg = 0; rg < 4; rg++) {
      const int row = m0 + wr * 32 + mi * 16 + lr + rg;
#pragma unroll
      for (int nj = 0; nj < 2; nj++) {
        const int col = n0 + wc * 32 + nj * 16 + fr;
        pbase[((size_t)(e * ROWS) + row) * O_ + col] = acc[mi][nj][rg];
      }
    }
}

// ---------- combine: out[tok] = sum_e gate * (p0 + p1 + b2[e]) ; atomic-free ----------
__global__ void combine_kernel(const float* __restrict__ part, const int* __restrict__ entry,
                               const float* __restrict__ gate, const float* __restrict__ b2,
                               float* __restrict__ out) {
  const int tok = blockIdx.x;
  const int c = threadIdx.x * 4;
  float4 acc = {0.f, 0.f, 0.f, 0.f};
#pragma unroll
  for (int e = 0; e < E_; e++) {
    const int r1 = entry[tok * E_ + e];
    if (r1) {
      const int idx = e * ROWS + (r1 - 1);
      const float g = gate[idx];
      const float4 p0 = *(const float4*)&part[(size_t)idx * O_ + c];
      const float4 p1 = *(const float4*)&part[(size_t)(E_ * ROWS + idx) * O_ + c];
      const float4 bb = *(const float4*)&b2[e * O_ + c];
      acc.x += g * (p0.x + p1.x + bb.x);
      acc.y += g * (p0.y + p1.y + bb.y);
      acc.z += g * (p0.z + p1.z + bb.z);
      acc.w += g * (p0.w + p1.w + bb.w);
    }
  }
  *(float4*)&out[(size_t)tok * O_ + c] = acc;
}

// ---------- launch ----------
extern "C" void kernel_launch(void* const* d_in, const int* in_sizes, int n_in,
                              void* d_out, int out_size, void* d_ws, size_t ws_size,
                              hipStream_t stream) {
  const float* x     = (const float*)d_in[0];
  const float* wg    = (const float*)d_in[1];
  const float* w1    = (const float*)d_in[2];
  const float* b1    = (const float*)d_in[3];
  const float* g_ln  = (const float*)d_in[4];
  const float* b_ln  = (const float*)d_in[5];
  const float* w2    = (const float*)d_in[6];
  const float* b2    = (const float*)d_in[7];
  float* out = (float*)d_out;
  float* out_logits = out + (size_t)NTOK * O_;

  char* wsb = (char*)d_ws;
  unsigned short* xb   = (unsigned short*)(wsb + 0);          // 8,388,608 B
  unsigned short* w1t  = (unsigned short*)(wsb + 8388608);    // 33,554,432 B (reused as part)
  unsigned short* w2t  = (unsigned short*)(wsb + 41943040);   // 33,554,432 B
  unsigned short* hbuf = (unsigned short*)(wsb + 75497472);   // 16,777,216 B
  float* probs = (float*)(wsb + 92274688);                    // 131,072 B
  int*   sel   = (int*)  (wsb + 92405760);                    // 16,384 B
  float* gate  = (float*)(wsb + 92422144);                    // 16,384 B
  int*   entry = (int*)  (wsb + 92438528);                    // 131,072 B
  float* part  = (float*)(wsb + 8388608);                     // aliases w1t (dead after gemm1)

  gating_kernel<<<NTOK / 4, 256, 0, stream>>>(x, wg, out_logits, probs, xb);
  transpose_both_kernel<<<2048, 256, 0, stream>>>(w1, w1t, w2, w2t);
  topk_kernel<<<2 * E_ * 8, 256, 0, stream>>>(out_logits, probs, sel, gate, entry);
  gemm1_kernel<<<(F_ / BN) * (ROWS / BM) * E_, 256, 0, stream>>>(xb, w1t, b1, sel, hbuf);
  ln_kernel<<<E_ * ROWS, 256, 0, stream>>>(hbuf, g_ln, b_ln);
  gemm2_partial_kernel<<<2048, 256, 0, stream>>>(hbuf, w2t, part);
  combine_kernel<<<NTOK, 256, 0, stream>>>(part, entry, gate, b2, out);
}

// Round 16
// 148.608 us; speedup vs baseline: 1.2150x; 1.0070x over previous
//
#include <hip/hip_runtime.h>
#include <cstdint>
#include <cstddef>

typedef __attribute__((ext_vector_type(8))) short bf16x8;
typedef __attribute__((ext_vector_type(4))) float f32x4;

#define S_    2048
#define D_    1024
#define F_    2048
#define O_    1024
#define E_    8
#define KCAP  256
#define ROWS  512           // 2 batches * KCAP per expert
#define NTOK  4096          // B*S

#define BM 64
#define BN 64
#define BK 64
#define TILE_ELEMS (BM * BK)

// ---------- bf16 helpers ----------
__device__ __forceinline__ unsigned short f2bf(float f) {
  unsigned int u = __float_as_uint(f);
  u = (u + 0x7fffu + ((u >> 16) & 1u)) >> 16;   // RNE
  return (unsigned short)u;
}
__device__ __forceinline__ float bf2f(unsigned short h) {
  return __uint_as_float(((unsigned int)h) << 16);
}

// ---------- async global->LDS, 16B per lane, wave-uniform LDS base ----------
__device__ __forceinline__ void gload16(void* lds, const void* g) {
  auto gp = (__attribute__((address_space(1))) unsigned int*)(uintptr_t)g;
  auto lp = (__attribute__((address_space(3))) unsigned int*)(unsigned int)(uintptr_t)lds;
  __builtin_amdgcn_global_load_lds(gp, lp, 16, 0, 0);
}

// ---------- gating: logits (fp64 accum) + softmax probs + x->bf16 ----------
__global__ void gating_kernel(const float* __restrict__ x, const float* __restrict__ wg,
                              float* __restrict__ logits, float* __restrict__ probs,
                              unsigned short* __restrict__ xb) {
  const int wave = threadIdx.x >> 6, lane = threadIdx.x & 63;
  const int t = blockIdx.x * 4 + wave;
  const float* xr = x + (size_t)t * D_;
  double acc[8] = {0, 0, 0, 0, 0, 0, 0, 0};
  const int d0 = lane * 16;
#pragma unroll
  for (int i = 0; i < 4; i++) {
    float4 xv = *(const float4*)&xr[d0 + i * 4];
    union { ushort4 u4; unsigned short u[4]; } cv;
    cv.u[0] = f2bf(xv.x); cv.u[1] = f2bf(xv.y); cv.u[2] = f2bf(xv.z); cv.u[3] = f2bf(xv.w);
    *(ushort4*)&xb[(size_t)t * D_ + d0 + i * 4] = cv.u4;
    float xs[4] = {xv.x, xv.y, xv.z, xv.w};
#pragma unroll
    for (int j = 0; j < 4; j++) {
      const float4* wr = (const float4*)&wg[(size_t)(d0 + i * 4 + j) * 8];
      float4 w0 = wr[0], w1v = wr[1];
      double xd = (double)xs[j];
      acc[0] += xd * (double)w0.x;  acc[1] += xd * (double)w0.y;
      acc[2] += xd * (double)w0.z;  acc[3] += xd * (double)w0.w;
      acc[4] += xd * (double)w1v.x; acc[5] += xd * (double)w1v.y;
      acc[6] += xd * (double)w1v.z; acc[7] += xd * (double)w1v.w;
    }
  }
#pragma unroll
  for (int off = 32; off; off >>= 1) {
#pragma unroll
    for (int e = 0; e < 8; e++) acc[e] += __shfl_down(acc[e], off);
  }
  if (lane == 0) {
    double m = acc[0];
    for (int e = 1; e < 8; e++) m = acc[e] > m ? acc[e] : m;
    double p[8]; double s = 0;
    for (int e = 0; e < 8; e++) { p[e] = exp(acc[e] - m); s += p[e]; }
    const double inv = 1.0 / s;
    for (int e = 0; e < 8; e++) {
      logits[(size_t)t * 8 + e] = (float)acc[e];
      probs [(size_t)t * 8 + e] = (float)(p[e] * inv);
    }
  }
}

// ---------- merged transpose + fp32->bf16, 2 tiles/block, ENFORCED reg-prefetch ----------
// 4096 blocks; block b handles tiles {b (w1), b+4096 (w2)}.
// All 8 float4 loads issued up front; sched_barrier(0) pins them so the second
// tile's loads stay in flight under the first tile's LDS/store phase.
__global__ void transpose_both_kernel(const float* __restrict__ w1, unsigned short* __restrict__ w1t,
                                      const float* __restrict__ w2, unsigned short* __restrict__ w2t) {
  __shared__ float t[64][65];
  const int tid = threadIdx.x;
  const int lr = tid >> 4;          // 0..15
  const int lc = (tid & 15) * 4;    // 0..60
  const int r8 = (tid & 7) * 8;

  const float* inp[2]; unsigned short* outp[2]; int Rv[2], Cv[2], r0v[2], c0v[2];
  {
    // k = 0: w1 tile  ([D][F] -> [F][D]); 512 tiles/expert (32 C-panels x 16 R-panels)
    const int rem = blockIdx.x;
    const int e = rem >> 9, p = rem & 511;
    Rv[0] = D_; Cv[0] = F_;
    c0v[0] = (p & 31) * 64; r0v[0] = (p >> 5) * 64;
    inp[0] = w1 + (size_t)e * D_ * F_;  outp[0] = w1t + (size_t)e * D_ * F_;
    // k = 1: w2 tile  ([F][O] -> [O][F]); 512 tiles/expert (16 C-panels x 32 R-panels)
    Rv[1] = F_; Cv[1] = O_;
    c0v[1] = (p & 15) * 64; r0v[1] = (p >> 4) * 64;
    inp[1] = w2 + (size_t)e * F_ * O_;  outp[1] = w2t + (size_t)e * F_ * O_;
  }

  // issue ALL loads up front (32 VGPR payload), pinned by sched_barrier
  float4 v[2][4];
#pragma unroll
  for (int k = 0; k < 2; k++)
#pragma unroll
    for (int i = 0; i < 4; i++)
      v[k][i] = *(const float4*)&inp[k][(size_t)(r0v[k] + lr + i * 16) * Cv[k] + c0v[k] + lc];
  __builtin_amdgcn_sched_barrier(0);   // forbid sinking the loads into the loop below

#pragma unroll
  for (int k = 0; k < 2; k++) {
#pragma unroll
    for (int i = 0; i < 4; i++) {
      const int r = lr + i * 16;
      t[r][lc] = v[k][i].x; t[r][lc + 1] = v[k][i].y; t[r][lc + 2] = v[k][i].z; t[r][lc + 3] = v[k][i].w;
    }
    __syncthreads();
#pragma unroll
    for (int it = 0; it < 2; it++) {
      const int c = (tid >> 3) + it * 32;
      union { bf16x8 vv; unsigned short u[8]; } o;
#pragma unroll
      for (int j = 0; j < 8; j++) o.u[j] = f2bf(t[r8 + j][c]);
      *(bf16x8*)&outp[k][(size_t)(c0v[k] + c) * Rv[k] + r0v[k] + r8] = o.vv;
    }
    __syncthreads();   // all reads of t done before next tile overwrites
  }
}

// ---------- expert-choice top-k + deterministic per-token inverse index ----------
__global__ void topk_kernel(const float* __restrict__ logits, const float* __restrict__ probs,
                            int* __restrict__ sel, float* __restrict__ gate,
                            int* __restrict__ entry) {    // entry[tok][e] = row+1 (0 = absent)
  __shared__ unsigned int keys[S_];
  const int idx = blockIdx.x;       // 0..127 : (b,e) x 8 segments
  const int seg = idx & 7;
  const int be = idx >> 3;          // 0..15
  const int b = be >> 3;            // 0..1
  const int e = be & 7;
  const int tid = threadIdx.x;
  for (int i = tid; i < S_; i += 256) {
    unsigned int u = __float_as_uint(logits[((size_t)(b * S_ + i)) * E_ + e]);
    keys[i] = u ^ ((u & 0x80000000u) ? 0xFFFFFFFFu : 0x80000000u);
  }
  __syncthreads();
  const int s = seg * 256 + tid;
  const unsigned int vk = keys[s];
  const int wave = tid >> 6;
  const int W0 = seg * 256 + wave * 64;
  int rank = 0;
#pragma unroll 4
  for (int i = 0; i < W0; i += 4) {
    const uint4 kv = *(const uint4*)&keys[i];
    rank += (kv.x >= vk) + (kv.y >= vk) + (kv.z >= vk) + (kv.w >= vk);
  }
#pragma unroll
  for (int j = 0; j < 64; j++) {
    const int i = W0 + j;
    const unsigned int kv = keys[i];
    rank += (kv > vk) || (kv == vk && i < s);
  }
#pragma unroll 4
  for (int i = W0 + 64; i < S_; i += 4) {
    const uint4 kv = *(const uint4*)&keys[i];
    rank += (kv.x > vk) + (kv.y > vk) + (kv.z > vk) + (kv.w > vk);
  }
  const int tok = b * S_ + s;
  if (rank < KCAP) {
    const int row = b * KCAP + rank;
    sel  [e * ROWS + row] = tok;
    gate [e * ROWS + row] = probs[(size_t)tok * E_ + e];
    entry[tok * E_ + e]   = row + 1;
  } else {
    entry[tok * E_ + e]   = 0;
  }
}

// ====================== GEMM1 (D1): single-buffer, 8 blocks/CU ======================
__global__ __launch_bounds__(256, 8) void gemm1_kernel(
    const unsigned short* __restrict__ xb, const unsigned short* __restrict__ w1t,
    const float* __restrict__ b1, const int* __restrict__ sel,
    unsigned short* __restrict__ hbuf) {
  __shared__ unsigned short As[TILE_ELEMS];   // 8 KB
  __shared__ unsigned short Bs[TILE_ELEMS];   // 8 KB
  const int bid = blockIdx.x;
  const int lid = (bid & 7) * 256 + (bid >> 3);
  const int e   = lid >> 8;
  const int rem = lid & 255;
  const int n0  = (rem >> 3) * BN;
  const int m0  = (rem & 7) * BM;
  const int tid = threadIdx.x;
  const int wave = tid >> 6, lane = tid & 63;
  const int wr = wave >> 1, wc = wave & 1;

  const int srow = lane >> 3;
  const int schunk = (lane & 7) ^ srow;
  const unsigned short* asrc[2];
  const unsigned short* bsrc[2];
#pragma unroll
  for (int j = 0; j < 2; j++) {
    const int r = wave * 16 + j * 8 + srow;
    const int tok = sel[e * ROWS + m0 + r];
    asrc[j] = xb + (size_t)tok * D_ + schunk * 8;
    bsrc[j] = w1t + ((size_t)e * F_ + n0 + r) * D_ + schunk * 8;
  }

  f32x4 acc[2][2];
#pragma unroll
  for (int mi = 0; mi < 2; mi++)
#pragma unroll
    for (int nj = 0; nj < 2; nj++) acc[mi][nj] = (f32x4){0.f, 0.f, 0.f, 0.f};

  const int fr = lane & 15;

  for (int t = 0; t < D_ / BK; t++) {
    const int k0 = t * BK;
#pragma unroll
    for (int j = 0; j < 2; j++) {
      gload16(&As[(wave * 16 + j * 8) * BK], asrc[j] + k0);
      gload16(&Bs[(wave * 16 + j * 8) * BK], bsrc[j] + k0);
    }
    __syncthreads();                 // staging complete (implicit vmcnt(0))
    bf16x8 a[2][2], b[2][2];
#pragma unroll
    for (int kk = 0; kk < 2; kk++) {
      const int xch = ((kk * 4 + (lane >> 4)) ^ (lane & 7)) * 8;
#pragma unroll
      for (int mi = 0; mi < 2; mi++)
        a[kk][mi] = *(const bf16x8*)&As[(wr * 32 + mi * 16 + fr) * BK + xch];
#pragma unroll
      for (int nj = 0; nj < 2; nj++)
        b[kk][nj] = *(const bf16x8*)&Bs[(wc * 32 + nj * 16 + fr) * BK + xch];
    }
#pragma unroll
    for (int kk = 0; kk < 2; kk++)
#pragma unroll
      for (int mi = 0; mi < 2; mi++)
#pragma unroll
        for (int nj = 0; nj < 2; nj++)
          acc[mi][nj] = __builtin_amdgcn_mfma_f32_16x16x32_bf16(a[kk][mi], b[kk][nj], acc[mi][nj], 0, 0, 0);
    __syncthreads();                 // all waves done reading before next overwrite
  }

  const int lr = (lane >> 4) * 4;
#pragma unroll
  for (int mi = 0; mi < 2; mi++)
#pragma unroll
    for (int nj = 0; nj < 2; nj++)
#pragma unroll
      for (int rg = 0; rg < 4; rg++) {
        const int row = m0 + wr * 32 + mi * 16 + lr + rg;
        const int col = n0 + wc * 32 + nj * 16 + fr;
        float v = acc[mi][nj][rg] + b1[e * F_ + col];
        v = 0.5f * v * (1.0f + erff(v * 0.70710678118654752f));   // exact GELU
        hbuf[((size_t)e * ROWS + row) * F_ + col] = f2bf(v);
      }
}

// ---------- row LayerNorm over F_, in place on bf16 h ----------
__global__ void ln_kernel(unsigned short* __restrict__ hbuf,
                          const float* __restrict__ g_ln, const float* __restrict__ b_ln) {
  const int row = blockIdx.x;          // 0..E_*ROWS-1
  const int e = row >> 9;
  unsigned short* hr = hbuf + (size_t)row * F_;
  const int tid = threadIdx.x;
  union { bf16x8 v; unsigned short u[8]; } u;
  u.v = *(const bf16x8*)&hr[tid * 8];
  float vals[8]; float s1 = 0.f, s2 = 0.f;
#pragma unroll
  for (int j = 0; j < 8; j++) { float f = bf2f(u.u[j]); vals[j] = f; s1 += f; s2 += f * f; }
#pragma unroll
  for (int off = 32; off; off >>= 1) { s1 += __shfl_down(s1, off); s2 += __shfl_down(s2, off); }
  __shared__ float rs[8];
  const int wave = tid >> 6, lane = tid & 63;
  if (lane == 0) { rs[wave] = s1; rs[wave + 4] = s2; }
  __syncthreads();
  const float t1 = rs[0] + rs[1] + rs[2] + rs[3];
  const float t2 = rs[4] + rs[5] + rs[6] + rs[7];
  const float mu = t1 * (1.f / F_);
  const float var = t2 * (1.f / F_) - mu * mu;   // biased var (jnp.var)
  const float rstd = rsqrtf(var + 1e-5f);
  const float4* gl4 = (const float4*)(g_ln + (size_t)e * F_ + tid * 8);
  const float4* bl4 = (const float4*)(b_ln + (size_t)e * F_ + tid * 8);
  float4 g0 = gl4[0], g1 = gl4[1], bb0 = bl4[0], bb1 = bl4[1];
  float gs[8] = {g0.x, g0.y, g0.z, g0.w, g1.x, g1.y, g1.z, g1.w};
  float bs[8] = {bb0.x, bb0.y, bb0.z, bb0.w, bb1.x, bb1.y, bb1.z, bb1.w};
  union { bf16x8 v; unsigned short u[8]; } o;
#pragma unroll
  for (int j = 0; j < 8; j++)
    o.u[j] = f2bf((vals[j] - mu) * rstd * gs[j] + bs[j]);
  *(bf16x8*)&hr[tid * 8] = o.v;
}

// ====================== GEMM2 partial: split-K x2, D1 structure, plain stores ======================
__global__ __launch_bounds__(256, 8) void gemm2_partial_kernel(
    const unsigned short* __restrict__ hbuf, // [E][ROWS][F_]
    const unsigned short* __restrict__ w2t,  // [E][O_][F_]
    float* __restrict__ part) {              // [2][E_*ROWS][O_]
  __shared__ unsigned short As[TILE_ELEMS];
  __shared__ unsigned short Bs[TILE_ELEMS];
  const int bid = blockIdx.x;
  const int lid = (bid & 7) * 256 + (bid >> 3);   // 8 XCDs x 256; expert-per-XCD
  const int e     = lid >> 8;
  const int rem   = lid & 255;
  const int khalf = rem & 1;
  const int m0    = ((rem >> 1) & 7) * BM;
  const int n0    = (rem >> 4) * BN;              // 16 O panels
  const int koff  = khalf * (F_ / 2);
  const int tid = threadIdx.x;
  const int wave = tid >> 6, lane = tid & 63;
  const int wr = wave >> 1, wc = wave & 1;

  const int srow = lane >> 3;
  const int schunk = (lane & 7) ^ srow;
  const unsigned short* asrc[2];
  const unsigned short* bsrc[2];
#pragma unroll
  for (int j = 0; j < 2; j++) {
    const int r = wave * 16 + j * 8 + srow;
    asrc[j] = hbuf + ((size_t)e * ROWS + m0 + r) * F_ + koff + schunk * 8;
    bsrc[j] = w2t + ((size_t)e * O_ + n0 + r) * F_ + koff + schunk * 8;
  }

  f32x4 acc[2][2];
#pragma unroll
  for (int mi = 0; mi < 2; mi++)
#pragma unroll
    for (int nj = 0; nj < 2; nj++) acc[mi][nj] = (f32x4){0.f, 0.f, 0.f, 0.f};

  const int fr = lane & 15;

  for (int t = 0; t < (F_ / 2) / BK; t++) {   // 16 steps
    const int k0 = t * BK;
#pragma unroll
    for (int j = 0; j < 2; j++) {
      gload16(&As[(wave * 16 + j * 8) * BK], asrc[j] + k0);
      gload16(&Bs[(wave * 16 + j * 8) * BK], bsrc[j] + k0);
    }
    __syncthreads();
    bf16x8 a[2][2], b[2][2];
#pragma unroll
    for (int kk = 0; kk < 2; kk++) {
      const int xch = ((kk * 4 + (lane >> 4)) ^ (lane & 7)) * 8;
#pragma unroll
      for (int mi = 0; mi < 2; mi++)
        a[kk][mi] = *(const bf16x8*)&As[(wr * 32 + mi * 16 + fr) * BK + xch];
#pragma unroll
      for (int nj = 0; nj < 2; nj++)
        b[kk][nj] = *(const bf16x8*)&Bs[(wc * 32 + nj * 16 + fr) * BK + xch];
    }
#pragma unroll
    for (int kk = 0; kk < 2; kk++)
#pragma unroll
      for (int mi = 0; mi < 2; mi++)
#pragma unroll
        for (int nj = 0; nj < 2; nj++)
          acc[mi][nj] = __builtin_amdgcn_mfma_f32_16x16x32_bf16(a[kk][mi], b[kk][nj], acc[mi][nj], 0, 0, 0);
    __syncthreads();
  }

  float* pbase = part + (size_t)khalf * (E_ * ROWS) * O_;
  const int lr = (lane >> 4) * 4;
#pragma unroll
  for (int mi = 0; mi < 2; mi++)
#pragma unroll
    for (int rg = 0; rg < 4; rg++) {
      const int row = m0 + wr * 32 + mi * 16 + lr + rg;
#pragma unroll
      for (int nj = 0; nj < 2; nj++) {
        const int col = n0 + wc * 32 + nj * 16 + fr;
        pbase[((size_t)(e * ROWS) + row) * O_ + col] = acc[mi][nj][rg];
      }
    }
}

// ---------- combine: out[tok] = sum_e gate * (p0 + p1 + b2[e]) ; atomic-free ----------
__global__ void combine_kernel(const float* __restrict__ part, const int* __restrict__ entry,
                               const float* __restrict__ gate, const float* __restrict__ b2,
                               float* __restrict__ out) {
  const int tok = blockIdx.x;
  const int c = threadIdx.x * 4;
  float4 acc = {0.f, 0.f, 0.f, 0.f};
#pragma unroll
  for (int e = 0; e < E_; e++) {
    const int r1 = entry[tok * E_ + e];
    if (r1) {
      const int idx = e * ROWS + (r1 - 1);
      const float g = gate[idx];
      const float4 p0 = *(const float4*)&part[(size_t)idx * O_ + c];
      const float4 p1 = *(const float4*)&part[(size_t)(E_ * ROWS + idx) * O_ + c];
      const float4 bb = *(const float4*)&b2[e * O_ + c];
      acc.x += g * (p0.x + p1.x + bb.x);
      acc.y += g * (p0.y + p1.y + bb.y);
      acc.z += g * (p0.z + p1.z + bb.z);
      acc.w += g * (p0.w + p1.w + bb.w);
    }
  }
  *(float4*)&out[(size_t)tok * O_ + c] = acc;
}

// ---------- launch ----------
extern "C" void kernel_launch(void* const* d_in, const int* in_sizes, int n_in,
                              void* d_out, int out_size, void* d_ws, size_t ws_size,
                              hipStream_t stream) {
  const float* x     = (const float*)d_in[0];
  const float* wg    = (const float*)d_in[1];
  const float* w1    = (const float*)d_in[2];
  const float* b1    = (const float*)d_in[3];
  const float* g_ln  = (const float*)d_in[4];
  const float* b_ln  = (const float*)d_in[5];
  const float* w2    = (const float*)d_in[6];
  const float* b2    = (const float*)d_in[7];
  float* out = (float*)d_out;
  float* out_logits = out + (size_t)NTOK * O_;

  char* wsb = (char*)d_ws;
  unsigned short* xb   = (unsigned short*)(wsb + 0);          // 8,388,608 B
  unsigned short* w1t  = (unsigned short*)(wsb + 8388608);    // 33,554,432 B (reused as part)
  unsigned short* w2t  = (unsigned short*)(wsb + 41943040);   // 33,554,432 B
  unsigned short* hbuf = (unsigned short*)(wsb + 75497472);   // 16,777,216 B
  float* probs = (float*)(wsb + 92274688);                    // 131,072 B
  int*   sel   = (int*)  (wsb + 92405760);                    // 16,384 B
  float* gate  = (float*)(wsb + 92422144);                    // 16,384 B
  int*   entry = (int*)  (wsb + 92438528);                    // 131,072 B
  float* part  = (float*)(wsb + 8388608);                     // aliases w1t (dead after gemm1)

  gating_kernel<<<NTOK / 4, 256, 0, stream>>>(x, wg, out_logits, probs, xb);
  transpose_both_kernel<<<4096, 256, 0, stream>>>(w1, w1t, w2, w2t);
  topk_kernel<<<2 * E_ * 8, 256, 0, stream>>>(out_logits, probs, sel, gate, entry);
  gemm1_kernel<<<(F_ / BN) * (ROWS / BM) * E_, 256, 0, stream>>>(xb, w1t, b1, sel, hbuf);
  ln_kernel<<<E_ * ROWS, 256, 0, stream>>>(hbuf, g_ln, b_ln);
  gemm2_partial_kernel<<<2048, 256, 0, stream>>>(hbuf, w2t, part);
  combine_kernel<<<NTOK, 256, 0, stream>>>(part, entry, gate, b2, out);
}